// Round 6
// baseline (949.610 us; speedup 1.0000x reference)
//
#include <hip/hip_runtime.h>
#include <cstdint>
#include <cstddef>

// ---------------------------------------------------------------------------
// RunLengthEventTransformerEmbedding  (B=8,T=4096,C=8,E=1024,D=512,F=2048,L=4)
// R6: GEMM split-K for N=512 (2-4 blocks/CU, atomic fp32 epilogue) + XOR bank
//     swizzle on GEMM LDS tiles (8-way -> 2-way = free). Rest as R5.
// ---------------------------------------------------------------------------

typedef __attribute__((ext_vector_type(8))) short short8;   // 8 x bf16 (4 VGPR)
typedef __attribute__((ext_vector_type(4))) float f32x4;

#define DEVINL __device__ __forceinline__

DEVINL short f2bf(float f) {               // fp32 -> bf16 RNE (finite inputs)
  union { float f; unsigned u; } v; v.f = f;
  unsigned u = v.u + 0x7fffu + ((v.u >> 16) & 1u);
  return (short)(u >> 16);
}

DEVINL unsigned bfpack(float lo, float hi) {  // two fp32 -> packed bf16x2 (trunc)
  union { float f; unsigned u; } a, b; a.f = lo; b.f = hi;
  return (a.u >> 16) | (b.u & 0xFFFF0000u);
}

DEVINL void gld_lds16(const void* g, void* l) {
  // async global->LDS, 16B/lane; LDS dest is wave-uniform base + lane*16
  __builtin_amdgcn_global_load_lds(
      (const __attribute__((address_space(1))) void*)g,
      (__attribute__((address_space(3))) void*)l, 16, 0, 0);
}

// ----------------------------- constants -----------------------------------
static constexpr int Bq = 8, T = 4096, C = 8, E = 1024, D = 512, F = 2048;
static constexpr int NL = 4, NH = 8, DH = 64, M = Bq * E;   // 8192 tokens
static constexpr float QSCALE = 0.18033688011112042f;       // 0.125 * log2(e)

// workspace offsets (bytes)
static constexpr size_t OFF_H    = 0;                        // f32 [8192,512]  16MB
static constexpr size_t OFF_Z    = OFF_H    + (size_t)16*1024*1024;  // bf16 [8192,512]   8MB
static constexpr size_t OFF_QKV  = OFF_Z    + (size_t)8*1024*1024;   // bf16 [8192,1536] 24MB
static constexpr size_t OFF_ATT  = OFF_QKV  + (size_t)24*1024*1024;  // bf16 [8192,512]   8MB
static constexpr size_t OFF_U    = OFF_ATT  + (size_t)8*1024*1024;   // bf16 [8192,2048] 32MB
                                   // OFF_U doubles as: vt bf16 [8,8,64,1024] (8MB, during attn)
                                   // and f32 tmp [8192,512] (16MB, after last FFN)
static constexpr size_t OFF_WQKV = OFF_U    + (size_t)32*1024*1024;  // bf16 [4][1536,512] 6MB
static constexpr size_t OFF_WO   = OFF_WQKV + (size_t)6*1024*1024;   // bf16 [4][512,512]  2MB
static constexpr size_t OFF_W1   = OFF_WO   + (size_t)2*1024*1024;   // bf16 [4][2048,512] 8MB
static constexpr size_t OFF_W2   = OFF_W1   + (size_t)8*1024*1024;   // bf16 [4][512,2048] 8MB
static constexpr size_t OFF_EV   = OFF_W2   + (size_t)8*1024*1024;   // int4 events [8192] 128KB
static constexpr size_t OFF_NEV  = OFF_EV   + (size_t)131072;        // int [8]
static constexpr size_t OFF_XW   = OFF_NEV  + (size_t)256;           // u32 [8,1024] 32KB

// ------------------ fused weight transpose + bf16 convert -------------------
__global__ void tconv_all_kernel(const float* __restrict__ wq, const float* __restrict__ wk,
                                 const float* __restrict__ wv, const float* __restrict__ wo,
                                 const float* __restrict__ w1, const float* __restrict__ w2,
                                 short* __restrict__ wqkv_t, short* __restrict__ wo_t,
                                 short* __restrict__ w1_t, short* __restrict__ w2_t) {
  int bid = blockIdx.x;
  const float* src; short* dst; int N, K, tile;
  if (bid < 4096) {
    int which = bid >> 10, r = bid & 1023, l = r >> 8;
    tile = r & 255; N = 512; K = 512;
    switch (which) {
      case 0:  src = wq + (size_t)l*262144; dst = wqkv_t + (size_t)l*786432;          break;
      case 1:  src = wk + (size_t)l*262144; dst = wqkv_t + (size_t)l*786432 + 262144; break;
      case 2:  src = wv + (size_t)l*262144; dst = wqkv_t + (size_t)l*786432 + 524288; break;
      default: src = wo + (size_t)l*262144; dst = wo_t   + (size_t)l*262144;          break;
    }
  } else if (bid < 8192) {
    int r = bid - 4096, l = r >> 10; tile = r & 1023;
    N = 2048; K = 512;
    src = w1 + (size_t)l*1048576; dst = w1_t + (size_t)l*1048576;
  } else {
    int r = bid - 8192, l = r >> 10; tile = r & 1023;
    N = 512; K = 2048;
    src = w2 + (size_t)l*1048576; dst = w2_t + (size_t)l*1048576;
  }
  int tiles_n = N >> 5;
  int n0 = (tile % tiles_n) * 32, k0 = (tile / tiles_n) * 32;
  __shared__ float tile_s[32][33];
  int tx = threadIdx.x, ty = threadIdx.y;
#pragma unroll
  for (int s = 0; s < 4; ++s)
    tile_s[ty + 8*s][tx] = src[(size_t)(k0 + ty + 8*s) * N + n0 + tx];
  __syncthreads();
#pragma unroll
  for (int s = 0; s < 4; ++s)
    dst[(size_t)(n0 + ty + 8*s) * K + k0 + tx] = f2bf(tile_s[tx][ty + 8*s]);
}

// ------------------------------ bit packing ---------------------------------
__global__ void xpack_kernel(const float* __restrict__ x, unsigned* __restrict__ xw) {
  __shared__ unsigned char sb[256];
  int idx = blockIdx.x * 256 + threadIdx.x;    // byte index = b*4096 + t
  const float* p = x + (size_t)idx * 8;
  f32x4 a = *(const f32x4*)p, b = *(const f32x4*)(p + 4);
  unsigned byte = 0;
#pragma unroll
  for (int j = 0; j < 4; ++j) {
    byte |= (a[j] > 0.5f ? 1u : 0u) << j;
    byte |= (b[j] > 0.5f ? 1u : 0u) << (j + 4);
  }
  sb[threadIdx.x] = (unsigned char)byte;
  __syncthreads();
  if (threadIdx.x < 64)
    xw[blockIdx.x * 64 + threadIdx.x] = *(const unsigned*)(sb + threadIdx.x * 4);
}

// ------------------------------ event scan ----------------------------------
__global__ void events_kernel(const unsigned* __restrict__ xw,
                              int4* __restrict__ ev4, int* __restrict__ n_events) {
  int b = blockIdx.x, tid = threadIdx.x;
  int lane = tid & 63, wid = tid >> 6;
  __shared__ int wsum[16];
  const unsigned* xb = xw + b * 1024;
  unsigned word = xb[tid];
  unsigned prevtop = (tid > 0) ? (xb[tid - 1] >> 24) : 0u;
  unsigned flags = word ^ ((word << 8) | prevtop);
  if (tid == 0) flags |= 0xFFu;                 // t=0: every component starts
  int cnt = __builtin_popcount(flags);

  int v = cnt;                                  // wave inclusive scan
#pragma unroll
  for (int off = 1; off < 64; off <<= 1) {
    int u = __shfl_up(v, off);
    if (lane >= off) v += u;
  }
  if (lane == 63) wsum[wid] = v;
  __syncthreads();
  int base = 0;
  for (int w = 0; w < wid; ++w) base += wsum[w];
  if (tid == 1023) {
    int tot = base + v;
    n_events[b] = tot < E ? tot : E;
  }
  int rank = base + v - cnt;

  unsigned f = flags;
  while (f && rank < E) {
    int bit = __builtin_ctz(f); f &= f - 1;
    int tl = bit >> 3, c = bit & 7;
    int t = tid * 4 + tl;
    int st = (word >> bit) & 1;
    unsigned colm = 0x01010101u << c;
    unsigned above = (bit < 31) ? (flags & colm & (0xFFFFFFFFu << (bit + 1))) : 0u;
    int t2;
    if (above) {
      int nb = __builtin_ctz(above);
      t2 = tid * 4 + ((nb - c) >> 3);
    } else {
      t2 = T;
      for (int w2 = tid + 1; w2 < 1024; ++w2) {
        unsigned nw = xb[w2];
        unsigned fl2 = nw ^ ((nw << 8) | (xb[w2 - 1] >> 24));
        unsigned m2 = fl2 & colm;
        if (m2) { t2 = w2 * 4 + ((__builtin_ctz(m2) - c) >> 3); break; }
      }
    }
    ev4[(b << 10) + rank] = make_int4(c, st, t, t2 - t);
    ++rank;
  }
}

// ------------------------------- embedding ----------------------------------
__global__ void embed_kernel(const int4* __restrict__ ev4, const int* __restrict__ nev,
                             const float* __restrict__ pw, const float* __restrict__ pb,
                             float* __restrict__ h) {
  int row = blockIdx.x;
  int b = row >> 10, e = row & 1023;
  int d = threadIdx.x * 4;
  f32x4 acc = *(const f32x4*)(pb + d);
  if (e < nev[b]) {
    int4 e4 = ev4[row];
    float st = (float)e4.y;
    float sn = (float)e4.z * (1.f / 4095.f);
    float dn = (float)e4.w * (1.f / 4096.f);
    acc += *(const f32x4*)(pw + e4.x * D + d);
    acc += st * *(const f32x4*)(pw + 8*D + d);
    acc += sn * *(const f32x4*)(pw + 9*D + d);
    acc += dn * *(const f32x4*)(pw + 10*D + d);
  }
  *(f32x4*)(h + (size_t)row * D + d) = acc;
}

// ------------------------------- layernorm ----------------------------------
template<int OUTF>
__global__ void ln_kernel(const float* __restrict__ hp, const float* __restrict__ g,
                          const float* __restrict__ bb, void* __restrict__ out) {
  int row = blockIdx.x * 4 + (threadIdx.x >> 6);
  int lane = threadIdx.x & 63;
  int c0 = lane * 8;
  const float* hr = hp + (size_t)row * D;
  f32x4 a = *(const f32x4*)(hr + c0);
  f32x4 c = *(const f32x4*)(hr + c0 + 4);
  float s1 = a[0]+a[1]+a[2]+a[3] + c[0]+c[1]+c[2]+c[3];
  float s2 = a[0]*a[0]+a[1]*a[1]+a[2]*a[2]+a[3]*a[3]
           + c[0]*c[0]+c[1]*c[1]+c[2]*c[2]+c[3]*c[3];
#pragma unroll
  for (int off = 1; off < 64; off <<= 1) {
    s1 += __shfl_xor(s1, off);
    s2 += __shfl_xor(s2, off);
  }
  float mean = s1 * (1.f / 512.f);
  float var  = s2 * (1.f / 512.f) - mean * mean;
  float rstd = rsqrtf(var + 1e-5f);
  f32x4 g0 = *(const f32x4*)(g + c0),  g1 = *(const f32x4*)(g + c0 + 4);
  f32x4 b0 = *(const f32x4*)(bb + c0), b1 = *(const f32x4*)(bb + c0 + 4);
  f32x4 o0 = (a - mean) * rstd * g0 + b0;
  f32x4 o1 = (c - mean) * rstd * g1 + b1;
  if constexpr (OUTF == 0) {
    short8 o;
#pragma unroll
    for (int j = 0; j < 4; ++j) { o[j] = f2bf(o0[j]); o[4 + j] = f2bf(o1[j]); }
    *(short8*)((short*)out + (size_t)row * D + c0) = o;
  } else {
    float* op = (float*)out + (size_t)row * D + c0;
    *(f32x4*)op = o0;
    *(f32x4*)(op + 4) = o1;
  }
}

// ------------------------- V transpose (bf16) --------------------------------
__global__ void vtrans_kernel(const short* __restrict__ qkv, short* __restrict__ vt) {
  __shared__ short st[64 * 72];
  int et = blockIdx.x, h = blockIdx.y, b = blockIdx.z;
  int tid = threadIdx.x;
  int r8 = tid >> 3, c8 = (tid & 7) * 8;
#pragma unroll
  for (int p = 0; p < 2; ++p) {
    int e = r8 + p * 32;
    short8 v = *(const short8*)(qkv + (size_t)(b*1024 + et*64 + e) * 1536 + 1024 + h*64 + c8);
#pragma unroll
    for (int j = 0; j < 8; ++j) st[(c8 + j) * 72 + e] = v[j];
  }
  __syncthreads();
#pragma unroll
  for (int p = 0; p < 2; ++p) {
    int dd = r8 + p * 32;
    short8 o = *(const short8*)(st + dd * 72 + c8);
    *(short8*)(vt + ((size_t)((b*8 + h) * 64 + dd)) * 1024 + et * 64 + c8) = o;
  }
}

// --------------------------------- GEMM -------------------------------------
// C[M,N] = A[M,K] @ Bt[N,K]^T, bf16 in, fp32 acc. 128x128 tile, 4 waves x
// 64x64, double-buffered LDS (1 barrier/iter, prefetch in flight over MFMA).
// LDS chunk slots XOR-swizzled: slot = kc ^ ((row>>1)&3)  -> fragment reads
// hit all 8 bank-quads, 2 lanes each (2-way = free).
// MODE 0: bf16 store (cols<512 scaled by QSCALE). MODE 1: bias + fast GELU.
// MODE 2: fp32 atomic residual accumulate (+bias on z==0); split-K = gridDim.z.
template<int MODE>
__global__ __launch_bounds__(256, 4)
void gemm_kernel(const short* __restrict__ A, const short* __restrict__ Bt,
                 const float* __restrict__ bias, float* __restrict__ Cr,
                 short* __restrict__ O1, int N, int K) {
  __shared__ short a_s[2][128 * 32];
  __shared__ short b_s[2][128 * 32];
  const int tid = threadIdx.x;
  const int wid = tid >> 6, lane = tid & 63;
  const int quad = lane >> 4, l16 = lane & 15;
  const int m0 = blockIdx.y * 128, n0 = blockIdx.x * 128;
  const int wrow = wid >> 1, wcol = wid & 1;
  const int nk = K / (32 * gridDim.z);
  const int kt0 = blockIdx.z * nk;

  // per-thread staging geometry (2 chunks each for A and B per tile)
  const int row0 = tid >> 2, kc0 = tid & 3;          // chunk i = tid
  const int row1 = (tid + 256) >> 2;                 // chunk i = tid + 256
  const int ks0 = (kc0 ^ ((row0 >> 1) & 3)) * 8;     // swizzled k-offset (shorts)
  const int ks1 = (kc0 ^ ((row1 >> 1) & 3)) * 8;
  const int ldsoff0 = tid * 8 - lane * 8;            // shorts (wave-uniform base)
  const int ldsoff1 = (tid + 256) * 8 - lane * 8;

  auto stage = [&](int kt, int buf) {
    int k0 = kt * 32;
    gld_lds16(A  + (size_t)(m0 + row0) * K + k0 + ks0, a_s[buf] + ldsoff0);
    gld_lds16(A  + (size_t)(m0 + row1) * K + k0 + ks1, a_s[buf] + ldsoff1);
    gld_lds16(Bt + (size_t)(n0 + row0) * K + k0 + ks0, b_s[buf] + ldsoff0);
    gld_lds16(Bt + (size_t)(n0 + row1) * K + k0 + ks1, b_s[buf] + ldsoff1);
  };

  f32x4 acc[4][4] = {};

  stage(kt0, 0);
  asm volatile("s_waitcnt vmcnt(0)" ::: "memory");
  __syncthreads();

  for (int kt = 0; kt < nk; ++kt) {
    const int cur = kt & 1;
    const bool more = (kt + 1) < nk;
    if (more) stage(kt0 + kt + 1, cur ^ 1);

    short8 af[4], bf[4];
#pragma unroll
    for (int mi = 0; mi < 4; ++mi) {
      int row = wrow*64 + mi*16 + l16;
      int sw = quad ^ ((row >> 1) & 3);
      af[mi] = *(const short8*)(a_s[cur] + row * 32 + sw * 8);
    }
#pragma unroll
    for (int ni = 0; ni < 4; ++ni) {
      int row = wcol*64 + ni*16 + l16;
      int sw = quad ^ ((row >> 1) & 3);
      bf[ni] = *(const short8*)(b_s[cur] + row * 32 + sw * 8);
    }
#pragma unroll
    for (int mi = 0; mi < 4; ++mi)
#pragma unroll
      for (int ni = 0; ni < 4; ++ni)
        acc[mi][ni] = __builtin_amdgcn_mfma_f32_16x16x32_bf16(af[mi], bf[ni], acc[mi][ni], 0, 0, 0);

    if (more) {
      asm volatile("s_waitcnt vmcnt(0)" ::: "memory");
      __syncthreads();
    }
  }

  const int mb = m0 + wrow * 64, nb = n0 + wcol * 64;
#pragma unroll
  for (int mi = 0; mi < 4; ++mi) {
#pragma unroll
    for (int ni = 0; ni < 4; ++ni) {
      int nn = nb + ni * 16 + l16;
#pragma unroll
      for (int r = 0; r < 4; ++r) {
        int mm = mb + mi * 16 + quad * 4 + r;   // C/D: col=lane&15, row=quad*4+reg
        float cv = acc[mi][ni][r];
        if constexpr (MODE == 0) {
          float ov = (nn < 512) ? cv * QSCALE : cv;  // fold softmax scale*log2e into Q
          union { float f; unsigned u; } vv; vv.f = ov;
          O1[(size_t)mm * N + nn] = (short)(vv.u >> 16);
        } else if constexpr (MODE == 1) {
          float xv = cv + bias[nn];
          float x3 = xv * (1.f + 0.044715f * xv * xv);
          float ez = __builtin_amdgcn_exp2f(-2.3022082299f * x3);
          float gv = xv * __builtin_amdgcn_rcpf(1.f + ez);
          union { float f; unsigned u; } vv; vv.f = gv;
          O1[(size_t)mm * N + nn] = (short)(vv.u >> 16);
        } else {
          float add = cv + ((bias && blockIdx.z == 0) ? bias[nn] : 0.f);
          atomicAdd(&Cr[(size_t)mm * N + nn], add);   // split-K partial
        }
      }
    }
  }
}

// ------------------------------- attention ----------------------------------
// block = (qt 64-row tile, head, batch); 4 waves, wave = 16 q-rows, k-tile 64.
// Computes S^T = mfma(A=K, B=Q): lane's 4 regs = 4 consecutive keys of one
// q-row -> P written as 4 x ds_write_b64 per kt; rowsum is lane-local scalar.
__global__ __launch_bounds__(256, 4)
void attn_kernel(const short* __restrict__ qkv, const short* __restrict__ vt,
                 short* __restrict__ att, const int* __restrict__ n_events) {
  __shared__ short q_s[64 * 64];     // [qrow][d], chunk-swizzled, wave-private bands
  __shared__ short k_s[64 * 64];     // [krow][d], chunk-swizzled
  __shared__ short vt_s[64 * 64];    // [d][key],  chunk-swizzled
  __shared__ short p_s[64 * 68];     // [qrow][key], pad +4, wave-private bands
  const int tid = threadIdx.x, wid = tid >> 6, lane = tid & 63;
  const int quad = lane >> 4, l16 = lane & 15;
  const int qt = blockIdx.x, h = blockIdx.y, b = blockIdx.z;
  const int ne = n_events[b];
  const int qbase = b * E + qt * 64;

  // stage this wave's own 16 Q rows (wave-private -> no barrier needed)
#pragma unroll
  for (int r = 0; r < 2; ++r) {
    int row = wid * 16 + r * 8 + (lane >> 3);
    int sz = lane & 7, dc = sz ^ (row & 7);
    gld_lds16(qkv + (size_t)(qbase + row) * 1536 + h * 64 + dc * 8,
              q_s + (wid * 16 + r * 8) * 64);
  }
  asm volatile("s_waitcnt vmcnt(0)" ::: "memory");

  short8 qf[2];                      // Q fragment (B-operand): loop-invariant
#pragma unroll
  for (int ks = 0; ks < 2; ++ks) {
    int row = wid * 16 + l16;
    int dc = (ks * 4 + quad) ^ (row & 7);
    qf[ks] = *(const short8*)(q_s + row * 64 + dc * 8);
  }

  f32x4 accO[4] = {};
  float rs = 0.f;                    // lane-local: sum over this lane's keys

  for (int kt = 0; kt < 16; ++kt) {
    __syncthreads();                         // prev iter done with k_s/vt_s
#pragma unroll
    for (int r = 0; r < 2; ++r) {
      int i = (r*4 + wid) * 64 + lane;
      int row = i >> 3, sz = i & 7, dc = sz ^ (row & 7);
      gld_lds16(qkv + (size_t)(b * E + kt * 64 + row) * 1536 + 512 + h * 64 + dc * 8,
                k_s + (r*4 + wid) * 512);
      gld_lds16(vt + (size_t)((b * 8 + h) * 64 + row) * 1024 + kt * 64 + dc * 8,
                vt_s + (r*4 + wid) * 512);
    }
    asm volatile("s_waitcnt vmcnt(0)" ::: "memory");
    __syncthreads();

    // ---- S^T = K Q^T: D[m=key][n=q], base-2 logits ----
    f32x4 accS[4] = {};
#pragma unroll
    for (int ni = 0; ni < 4; ++ni) {
#pragma unroll
      for (int ks = 0; ks < 2; ++ks) {
        int row = ni * 16 + l16;
        int dc = (ks * 4 + quad) ^ (row & 7);
        short8 kf = *(const short8*)(k_s + row * 64 + dc * 8);
        accS[ni] = __builtin_amdgcn_mfma_f32_16x16x32_bf16(kf, qf[ks], accS[ni], 0, 0, 0);
      }
    }

    // ---- softmax numerator (no max subtraction; logits O(1)) ----
    bool full = (kt * 64 + 64) <= ne;        // block-uniform branch
#pragma unroll
    for (int ni = 0; ni < 4; ++ni) {
      float p[4];
#pragma unroll
      for (int r = 0; r < 4; ++r) {
        bool masked = !full && (kt * 64 + ni * 16 + quad * 4 + r) >= ne;
        p[r] = masked ? 0.f : __builtin_amdgcn_exp2f(accS[ni][r]);
        rs += p[r];
      }
      unsigned w0 = bfpack(p[0], p[1]), w1 = bfpack(p[2], p[3]);
      int2 pk; pk.x = (int)w0; pk.y = (int)w1;
      *(int2*)(p_s + (wid * 16 + l16) * 68 + ni * 16 + quad * 4) = pk;
    }
    // p_s is wave-private: DS ops in-order within a wave -> no barrier.

    // ---- O += P V ----
    short8 ap[2];
#pragma unroll
    for (int ks = 0; ks < 2; ++ks)
      ap[ks] = *(const short8*)(p_s + (wid * 16 + l16) * 68 + ks * 32 + quad * 8);
#pragma unroll
    for (int di = 0; di < 4; ++di) {
#pragma unroll
      for (int ks = 0; ks < 2; ++ks) {
        int dd = di * 16 + l16;
        int dc = (ks * 4 + quad) ^ (dd & 7);
        short8 bv = *(const short8*)(vt_s + dd * 64 + dc * 8);
        accO[di] = __builtin_amdgcn_mfma_f32_16x16x32_bf16(ap[ks], bv, accO[di], 0, 0, 0);
      }
    }
  }

  // denom: reduce across the 4 quads (lanes sharing q = l16), then distribute
  rs += __shfl_xor(rs, 16);
  rs += __shfl_xor(rs, 32);
#pragma unroll
  for (int r = 0; r < 4; ++r) {
    float dv = __shfl(rs, quad * 4 + r);     // denom of q-row quad*4+r
    float linv = 1.f / (dv > 0.f ? dv : 1.f);
    int mm = qbase + wid * 16 + quad * 4 + r;
#pragma unroll
    for (int di = 0; di < 4; ++di)
      att[(size_t)mm * D + h * 64 + di * 16 + l16] = f2bf(accO[di][r] * linv);
  }
}

// ------------------------------ masked pool ---------------------------------
__global__ void pool_kernel(const float* __restrict__ tmp, const int* __restrict__ nev,
                            float* __restrict__ out) {
  __shared__ float red[512];
  int b = blockIdx.x >> 6, ch = blockIdx.x & 63;
  int n = nev[b];
  float inv = 1.f / (float)(n > 0 ? n : 1);
  int tid = threadIdx.x;
  int col = (tid & 127) * 4;
  int r0 = ch * 16 + (tid >> 7);
  f32x4 s = {0.f, 0.f, 0.f, 0.f};
#pragma unroll
  for (int i = 0; i < 8; ++i) {
    int e = r0 + i * 2;
    if (e < n) s += *(const f32x4*)(tmp + ((size_t)(b * E + e)) * D + col);
  }
  if (tid >= 128) *(f32x4*)(red + (tid - 128) * 4) = s;
  __syncthreads();
  if (tid < 128) {
    s += *(const f32x4*)(red + tid * 4);
#pragma unroll
    for (int j = 0; j < 4; ++j) atomicAdd(&out[b * D + col + j], s[j] * inv);
  }
}

// ------------------------------- launcher -----------------------------------
extern "C" void kernel_launch(void* const* d_in, const int* in_sizes, int n_in,
                              void* d_out, int out_size, void* d_ws, size_t ws_size,
                              hipStream_t stream) {
  (void)in_sizes; (void)n_in; (void)ws_size;
  const float* x      = (const float*)d_in[0];
  const float* proj_w = (const float*)d_in[1];
  const float* proj_b = (const float*)d_in[2];
  const float* wq     = (const float*)d_in[3];
  const float* wk     = (const float*)d_in[4];
  const float* wv     = (const float*)d_in[5];
  const float* wo     = (const float*)d_in[6];
  const float* ln1_g  = (const float*)d_in[7];
  const float* ln1_b  = (const float*)d_in[8];
  const float* w1     = (const float*)d_in[9];
  const float* b1     = (const float*)d_in[10];
  const float* w2     = (const float*)d_in[11];
  const float* b2     = (const float*)d_in[12];
  const float* ln2_g  = (const float*)d_in[13];
  const float* ln2_b  = (const float*)d_in[14];
  const float* lnf_g  = (const float*)d_in[15];
  const float* lnf_b  = (const float*)d_in[16];

  char* ws = (char*)d_ws;
  float* h      = (float*)(ws + OFF_H);
  short* z      = (short*)(ws + OFF_Z);
  short* qkv    = (short*)(ws + OFF_QKV);
  short* att    = (short*)(ws + OFF_ATT);
  short* u      = (short*)(ws + OFF_U);
  short* vt     = (short*)(ws + OFF_U);      // alias: live only QKV->attn
  float* tmp    = (float*)(ws + OFF_U);      // alias: live only after last FFN
  short* wqkv_t = (short*)(ws + OFF_WQKV);
  short* wo_t   = (short*)(ws + OFF_WO);
  short* w1_t   = (short*)(ws + OFF_W1);
  short* w2_t   = (short*)(ws + OFF_W2);
  int4*  ev4    = (int4*)(ws + OFF_EV);
  int*   n_ev   = (int*)(ws + OFF_NEV);
  unsigned* xw  = (unsigned*)(ws + OFF_XW);

  tconv_all_kernel<<<12288, dim3(32,8), 0, stream>>>(wq, wk, wv, wo, w1, w2,
                                                     wqkv_t, wo_t, w1_t, w2_t);
  xpack_kernel<<<128, 256, 0, stream>>>(x, xw);
  events_kernel<<<8, 1024, 0, stream>>>(xw, ev4, n_ev);
  embed_kernel<<<M, 128, 0, stream>>>(ev4, n_ev, proj_w, proj_b, h);

  for (int l = 0; l < NL; ++l) {
    ln_kernel<0><<<2048, 256, 0, stream>>>(h, ln1_g + l*D, ln1_b + l*D, z);
    gemm_kernel<0><<<dim3(12,64), 256, 0, stream>>>(z, wqkv_t + (size_t)l*786432, nullptr, nullptr, qkv, 1536, 512);
    vtrans_kernel<<<dim3(16,8,8), 256, 0, stream>>>(qkv, vt);
    attn_kernel<<<dim3(16,8,8), 256, 0, stream>>>(qkv, vt, att, n_ev);
    gemm_kernel<2><<<dim3(4,64,2), 256, 0, stream>>>(att, wo_t + (size_t)l*262144, nullptr, h, nullptr, 512, 512);
    ln_kernel<0><<<2048, 256, 0, stream>>>(h, ln2_g + l*D, ln2_b + l*D, z);
    gemm_kernel<1><<<dim3(16,64), 256, 0, stream>>>(z, w1_t + (size_t)l*1048576, b1 + l*F, nullptr, u, 2048, 512);
    gemm_kernel<2><<<dim3(4,64,4), 256, 0, stream>>>(u, w2_t + (size_t)l*1048576, b2 + l*D, h, nullptr, 512, 2048);
  }

  ln_kernel<1><<<2048, 256, 0, stream>>>(h, lnf_g, lnf_b, tmp);
  hipMemsetAsync(d_out, 0, (size_t)out_size * sizeof(float), stream);
  pool_kernel<<<512, 256, 0, stream>>>(tmp, n_ev, (float*)d_out);
}

// Round 7
// 797.601 us; speedup vs baseline: 1.1906x; 1.1906x over previous
//
#include <hip/hip_runtime.h>
#include <cstdint>
#include <cstddef>

// ---------------------------------------------------------------------------
// RunLengthEventTransformerEmbedding  (B=8,T=4096,C=8,E=1024,D=512,F=2048,L=4)
// R7: N=512 GEMMs -> 64x128-tile single-writer kernel (512 blocks, 2/CU, NO
//     atomics; R6's atomic split-K regressed via HBM RMW traffic). XOR bank
//     swizzle + pipelined dbuf kept everywhere.
// ---------------------------------------------------------------------------

typedef __attribute__((ext_vector_type(8))) short short8;   // 8 x bf16 (4 VGPR)
typedef __attribute__((ext_vector_type(4))) float f32x4;

#define DEVINL __device__ __forceinline__

DEVINL short f2bf(float f) {               // fp32 -> bf16 RNE (finite inputs)
  union { float f; unsigned u; } v; v.f = f;
  unsigned u = v.u + 0x7fffu + ((v.u >> 16) & 1u);
  return (short)(u >> 16);
}

DEVINL unsigned bfpack(float lo, float hi) {  // two fp32 -> packed bf16x2 (trunc)
  union { float f; unsigned u; } a, b; a.f = lo; b.f = hi;
  return (a.u >> 16) | (b.u & 0xFFFF0000u);
}

DEVINL void gld_lds16(const void* g, void* l) {
  // async global->LDS, 16B/lane; LDS dest is wave-uniform base + lane*16
  __builtin_amdgcn_global_load_lds(
      (const __attribute__((address_space(1))) void*)g,
      (__attribute__((address_space(3))) void*)l, 16, 0, 0);
}

// ----------------------------- constants -----------------------------------
static constexpr int Bq = 8, T = 4096, C = 8, E = 1024, D = 512, F = 2048;
static constexpr int NL = 4, NH = 8, DH = 64, M = Bq * E;   // 8192 tokens
static constexpr float QSCALE = 0.18033688011112042f;       // 0.125 * log2(e)

// workspace offsets (bytes)
static constexpr size_t OFF_H    = 0;                        // f32 [8192,512]  16MB
static constexpr size_t OFF_Z    = OFF_H    + (size_t)16*1024*1024;  // bf16 [8192,512]   8MB
static constexpr size_t OFF_QKV  = OFF_Z    + (size_t)8*1024*1024;   // bf16 [8192,1536] 24MB
static constexpr size_t OFF_ATT  = OFF_QKV  + (size_t)24*1024*1024;  // bf16 [8192,512]   8MB
static constexpr size_t OFF_U    = OFF_ATT  + (size_t)8*1024*1024;   // bf16 [8192,2048] 32MB
                                   // OFF_U doubles as: vt bf16 [8,8,64,1024] (8MB, during attn)
                                   // and f32 tmp [8192,512] (16MB, after last FFN)
static constexpr size_t OFF_WQKV = OFF_U    + (size_t)32*1024*1024;  // bf16 [4][1536,512] 6MB
static constexpr size_t OFF_WO   = OFF_WQKV + (size_t)6*1024*1024;   // bf16 [4][512,512]  2MB
static constexpr size_t OFF_W1   = OFF_WO   + (size_t)2*1024*1024;   // bf16 [4][2048,512] 8MB
static constexpr size_t OFF_W2   = OFF_W1   + (size_t)8*1024*1024;   // bf16 [4][512,2048] 8MB
static constexpr size_t OFF_EV   = OFF_W2   + (size_t)8*1024*1024;   // int4 events [8192] 128KB
static constexpr size_t OFF_NEV  = OFF_EV   + (size_t)131072;        // int [8]
static constexpr size_t OFF_XW   = OFF_NEV  + (size_t)256;           // u32 [8,1024] 32KB

// ------------------ fused weight transpose + bf16 convert -------------------
__global__ void tconv_all_kernel(const float* __restrict__ wq, const float* __restrict__ wk,
                                 const float* __restrict__ wv, const float* __restrict__ wo,
                                 const float* __restrict__ w1, const float* __restrict__ w2,
                                 short* __restrict__ wqkv_t, short* __restrict__ wo_t,
                                 short* __restrict__ w1_t, short* __restrict__ w2_t) {
  int bid = blockIdx.x;
  const float* src; short* dst; int N, K, tile;
  if (bid < 4096) {
    int which = bid >> 10, r = bid & 1023, l = r >> 8;
    tile = r & 255; N = 512; K = 512;
    switch (which) {
      case 0:  src = wq + (size_t)l*262144; dst = wqkv_t + (size_t)l*786432;          break;
      case 1:  src = wk + (size_t)l*262144; dst = wqkv_t + (size_t)l*786432 + 262144; break;
      case 2:  src = wv + (size_t)l*262144; dst = wqkv_t + (size_t)l*786432 + 524288; break;
      default: src = wo + (size_t)l*262144; dst = wo_t   + (size_t)l*262144;          break;
    }
  } else if (bid < 8192) {
    int r = bid - 4096, l = r >> 10; tile = r & 1023;
    N = 2048; K = 512;
    src = w1 + (size_t)l*1048576; dst = w1_t + (size_t)l*1048576;
  } else {
    int r = bid - 8192, l = r >> 10; tile = r & 1023;
    N = 512; K = 2048;
    src = w2 + (size_t)l*1048576; dst = w2_t + (size_t)l*1048576;
  }
  int tiles_n = N >> 5;
  int n0 = (tile % tiles_n) * 32, k0 = (tile / tiles_n) * 32;
  __shared__ float tile_s[32][33];
  int tx = threadIdx.x, ty = threadIdx.y;
#pragma unroll
  for (int s = 0; s < 4; ++s)
    tile_s[ty + 8*s][tx] = src[(size_t)(k0 + ty + 8*s) * N + n0 + tx];
  __syncthreads();
#pragma unroll
  for (int s = 0; s < 4; ++s)
    dst[(size_t)(n0 + ty + 8*s) * K + k0 + tx] = f2bf(tile_s[tx][ty + 8*s]);
}

// ------------------------------ bit packing ---------------------------------
__global__ void xpack_kernel(const float* __restrict__ x, unsigned* __restrict__ xw) {
  __shared__ unsigned char sb[256];
  int idx = blockIdx.x * 256 + threadIdx.x;    // byte index = b*4096 + t
  const float* p = x + (size_t)idx * 8;
  f32x4 a = *(const f32x4*)p, b = *(const f32x4*)(p + 4);
  unsigned byte = 0;
#pragma unroll
  for (int j = 0; j < 4; ++j) {
    byte |= (a[j] > 0.5f ? 1u : 0u) << j;
    byte |= (b[j] > 0.5f ? 1u : 0u) << (j + 4);
  }
  sb[threadIdx.x] = (unsigned char)byte;
  __syncthreads();
  if (threadIdx.x < 64)
    xw[blockIdx.x * 64 + threadIdx.x] = *(const unsigned*)(sb + threadIdx.x * 4);
}

// ------------------------------ event scan ----------------------------------
__global__ void events_kernel(const unsigned* __restrict__ xw,
                              int4* __restrict__ ev4, int* __restrict__ n_events) {
  int b = blockIdx.x, tid = threadIdx.x;
  int lane = tid & 63, wid = tid >> 6;
  __shared__ int wsum[16];
  const unsigned* xb = xw + b * 1024;
  unsigned word = xb[tid];
  unsigned prevtop = (tid > 0) ? (xb[tid - 1] >> 24) : 0u;
  unsigned flags = word ^ ((word << 8) | prevtop);
  if (tid == 0) flags |= 0xFFu;                 // t=0: every component starts
  int cnt = __builtin_popcount(flags);

  int v = cnt;                                  // wave inclusive scan
#pragma unroll
  for (int off = 1; off < 64; off <<= 1) {
    int u = __shfl_up(v, off);
    if (lane >= off) v += u;
  }
  if (lane == 63) wsum[wid] = v;
  __syncthreads();
  int base = 0;
  for (int w = 0; w < wid; ++w) base += wsum[w];
  if (tid == 1023) {
    int tot = base + v;
    n_events[b] = tot < E ? tot : E;
  }
  int rank = base + v - cnt;

  unsigned f = flags;
  while (f && rank < E) {
    int bit = __builtin_ctz(f); f &= f - 1;
    int tl = bit >> 3, c = bit & 7;
    int t = tid * 4 + tl;
    int st = (word >> bit) & 1;
    unsigned colm = 0x01010101u << c;
    unsigned above = (bit < 31) ? (flags & colm & (0xFFFFFFFFu << (bit + 1))) : 0u;
    int t2;
    if (above) {
      int nb = __builtin_ctz(above);
      t2 = tid * 4 + ((nb - c) >> 3);
    } else {
      t2 = T;
      for (int w2 = tid + 1; w2 < 1024; ++w2) {
        unsigned nw = xb[w2];
        unsigned fl2 = nw ^ ((nw << 8) | (xb[w2 - 1] >> 24));
        unsigned m2 = fl2 & colm;
        if (m2) { t2 = w2 * 4 + ((__builtin_ctz(m2) - c) >> 3); break; }
      }
    }
    ev4[(b << 10) + rank] = make_int4(c, st, t, t2 - t);
    ++rank;
  }
}

// ------------------------------- embedding ----------------------------------
__global__ void embed_kernel(const int4* __restrict__ ev4, const int* __restrict__ nev,
                             const float* __restrict__ pw, const float* __restrict__ pb,
                             float* __restrict__ h) {
  int row = blockIdx.x;
  int b = row >> 10, e = row & 1023;
  int d = threadIdx.x * 4;
  f32x4 acc = *(const f32x4*)(pb + d);
  if (e < nev[b]) {
    int4 e4 = ev4[row];
    float st = (float)e4.y;
    float sn = (float)e4.z * (1.f / 4095.f);
    float dn = (float)e4.w * (1.f / 4096.f);
    acc += *(const f32x4*)(pw + e4.x * D + d);
    acc += st * *(const f32x4*)(pw + 8*D + d);
    acc += sn * *(const f32x4*)(pw + 9*D + d);
    acc += dn * *(const f32x4*)(pw + 10*D + d);
  }
  *(f32x4*)(h + (size_t)row * D + d) = acc;
}

// ------------------------------- layernorm ----------------------------------
template<int OUTF>
__global__ void ln_kernel(const float* __restrict__ hp, const float* __restrict__ g,
                          const float* __restrict__ bb, void* __restrict__ out) {
  int row = blockIdx.x * 4 + (threadIdx.x >> 6);
  int lane = threadIdx.x & 63;
  int c0 = lane * 8;
  const float* hr = hp + (size_t)row * D;
  f32x4 a = *(const f32x4*)(hr + c0);
  f32x4 c = *(const f32x4*)(hr + c0 + 4);
  float s1 = a[0]+a[1]+a[2]+a[3] + c[0]+c[1]+c[2]+c[3];
  float s2 = a[0]*a[0]+a[1]*a[1]+a[2]*a[2]+a[3]*a[3]
           + c[0]*c[0]+c[1]*c[1]+c[2]*c[2]+c[3]*c[3];
#pragma unroll
  for (int off = 1; off < 64; off <<= 1) {
    s1 += __shfl_xor(s1, off);
    s2 += __shfl_xor(s2, off);
  }
  float mean = s1 * (1.f / 512.f);
  float var  = s2 * (1.f / 512.f) - mean * mean;
  float rstd = rsqrtf(var + 1e-5f);
  f32x4 g0 = *(const f32x4*)(g + c0),  g1 = *(const f32x4*)(g + c0 + 4);
  f32x4 b0 = *(const f32x4*)(bb + c0), b1 = *(const f32x4*)(bb + c0 + 4);
  f32x4 o0 = (a - mean) * rstd * g0 + b0;
  f32x4 o1 = (c - mean) * rstd * g1 + b1;
  if constexpr (OUTF == 0) {
    short8 o;
#pragma unroll
    for (int j = 0; j < 4; ++j) { o[j] = f2bf(o0[j]); o[4 + j] = f2bf(o1[j]); }
    *(short8*)((short*)out + (size_t)row * D + c0) = o;
  } else {
    float* op = (float*)out + (size_t)row * D + c0;
    *(f32x4*)op = o0;
    *(f32x4*)(op + 4) = o1;
  }
}

// ------------------------- V transpose (bf16) --------------------------------
__global__ void vtrans_kernel(const short* __restrict__ qkv, short* __restrict__ vt) {
  __shared__ short st[64 * 72];
  int et = blockIdx.x, h = blockIdx.y, b = blockIdx.z;
  int tid = threadIdx.x;
  int r8 = tid >> 3, c8 = (tid & 7) * 8;
#pragma unroll
  for (int p = 0; p < 2; ++p) {
    int e = r8 + p * 32;
    short8 v = *(const short8*)(qkv + (size_t)(b*1024 + et*64 + e) * 1536 + 1024 + h*64 + c8);
#pragma unroll
    for (int j = 0; j < 8; ++j) st[(c8 + j) * 72 + e] = v[j];
  }
  __syncthreads();
#pragma unroll
  for (int p = 0; p < 2; ++p) {
    int dd = r8 + p * 32;
    short8 o = *(const short8*)(st + dd * 72 + c8);
    *(short8*)(vt + ((size_t)((b*8 + h) * 64 + dd)) * 1024 + et * 64 + c8) = o;
  }
}

// ----------------------------- GEMM (128x128) --------------------------------
// C[M,N] = A[M,K] @ Bt[N,K]^T, bf16 in, fp32 acc. 4 waves x 64x64, pipelined
// dbuf (1 barrier/iter), XOR bank swizzle (2-way = free).
// MODE 0: bf16 store (cols<512 scaled by QSCALE). MODE 1: bias + fast GELU.
template<int MODE>
__global__ __launch_bounds__(256, 4)
void gemm_kernel(const short* __restrict__ A, const short* __restrict__ Bt,
                 const float* __restrict__ bias, short* __restrict__ O1,
                 int N, int K) {
  __shared__ short a_s[2][128 * 32];
  __shared__ short b_s[2][128 * 32];
  const int tid = threadIdx.x;
  const int wid = tid >> 6, lane = tid & 63;
  const int quad = lane >> 4, l16 = lane & 15;
  const int m0 = blockIdx.y * 128, n0 = blockIdx.x * 128;
  const int wrow = wid >> 1, wcol = wid & 1;
  const int nk = K >> 5;

  const int row0 = tid >> 2, kc0 = tid & 3;          // chunk i = tid
  const int row1 = (tid + 256) >> 2;                 // chunk i = tid + 256
  const int ks0 = (kc0 ^ ((row0 >> 1) & 3)) * 8;     // swizzled k-offset (shorts)
  const int ks1 = (kc0 ^ ((row1 >> 1) & 3)) * 8;
  const int ldsoff0 = tid * 8 - lane * 8;            // wave-uniform base
  const int ldsoff1 = (tid + 256) * 8 - lane * 8;

  auto stage = [&](int kt, int buf) {
    int k0 = kt * 32;
    gld_lds16(A  + (size_t)(m0 + row0) * K + k0 + ks0, a_s[buf] + ldsoff0);
    gld_lds16(A  + (size_t)(m0 + row1) * K + k0 + ks1, a_s[buf] + ldsoff1);
    gld_lds16(Bt + (size_t)(n0 + row0) * K + k0 + ks0, b_s[buf] + ldsoff0);
    gld_lds16(Bt + (size_t)(n0 + row1) * K + k0 + ks1, b_s[buf] + ldsoff1);
  };

  f32x4 acc[4][4] = {};

  stage(0, 0);
  asm volatile("s_waitcnt vmcnt(0)" ::: "memory");
  __syncthreads();

  for (int kt = 0; kt < nk; ++kt) {
    const int cur = kt & 1;
    const bool more = (kt + 1) < nk;
    if (more) stage(kt + 1, cur ^ 1);

    short8 af[4], bf[4];
#pragma unroll
    for (int mi = 0; mi < 4; ++mi) {
      int row = wrow*64 + mi*16 + l16;
      int sw = quad ^ ((row >> 1) & 3);
      af[mi] = *(const short8*)(a_s[cur] + row * 32 + sw * 8);
    }
#pragma unroll
    for (int ni = 0; ni < 4; ++ni) {
      int row = wcol*64 + ni*16 + l16;
      int sw = quad ^ ((row >> 1) & 3);
      bf[ni] = *(const short8*)(b_s[cur] + row * 32 + sw * 8);
    }
#pragma unroll
    for (int mi = 0; mi < 4; ++mi)
#pragma unroll
      for (int ni = 0; ni < 4; ++ni)
        acc[mi][ni] = __builtin_amdgcn_mfma_f32_16x16x32_bf16(af[mi], bf[ni], acc[mi][ni], 0, 0, 0);

    if (more) {
      asm volatile("s_waitcnt vmcnt(0)" ::: "memory");
      __syncthreads();
    }
  }

  const int mb = m0 + wrow * 64, nb = n0 + wcol * 64;
#pragma unroll
  for (int mi = 0; mi < 4; ++mi) {
#pragma unroll
    for (int ni = 0; ni < 4; ++ni) {
      int nn = nb + ni * 16 + l16;
#pragma unroll
      for (int r = 0; r < 4; ++r) {
        int mm = mb + mi * 16 + quad * 4 + r;   // C/D: col=lane&15, row=quad*4+reg
        float cv = acc[mi][ni][r];
        if constexpr (MODE == 0) {
          float ov = (nn < 512) ? cv * QSCALE : cv;  // fold softmax scale*log2e into Q
          union { float f; unsigned u; } vv; vv.f = ov;
          O1[(size_t)mm * N + nn] = (short)(vv.u >> 16);
        } else {
          float xv = cv + bias[nn];
          float x3 = xv * (1.f + 0.044715f * xv * xv);
          float ez = __builtin_amdgcn_exp2f(-2.3022082299f * x3);
          float gv = xv * __builtin_amdgcn_rcpf(1.f + ez);
          union { float f; unsigned u; } vv; vv.f = gv;
          O1[(size_t)mm * N + nn] = (short)(vv.u >> 16);
        }
      }
    }
  }
}

// ------------------------- GEMM 64x128 (residual) ----------------------------
// For N=512 outputs: tile 64m x 128n, 4 waves each 64m x 32n -> grid (N/128,
// M/64) = 512 blocks (2/CU). fp32 single-writer residual += (+bias). No atomics.
__global__ __launch_bounds__(256, 4)
void gemm64_kernel(const short* __restrict__ A, const short* __restrict__ Bt,
                   const float* __restrict__ bias, float* __restrict__ Cr,
                   int N, int K) {
  __shared__ short a_s[2][64 * 32];
  __shared__ short b_s[2][128 * 32];
  const int tid = threadIdx.x;
  const int wid = tid >> 6, lane = tid & 63;
  const int quad = lane >> 4, l16 = lane & 15;
  const int m0 = blockIdx.y * 64, n0 = blockIdx.x * 128;
  const int nk = K >> 5;

  // A: 256 chunks (1/thread); B: 512 chunks (2/thread)
  const int row0 = tid >> 2, kc0 = tid & 3;
  const int row1 = (tid + 256) >> 2;
  const int ksA  = (kc0 ^ (((row0 & 63) >> 1) & 3)) * 8;   // row0<64 for A
  const int ks0  = (kc0 ^ ((row0 >> 1) & 3)) * 8;
  const int ks1  = (kc0 ^ ((row1 >> 1) & 3)) * 8;
  const int ldsoff0 = tid * 8 - lane * 8;
  const int ldsoff1 = (tid + 256) * 8 - lane * 8;

  auto stage = [&](int kt, int buf) {
    int k0 = kt * 32;
    gld_lds16(A  + (size_t)(m0 + row0) * K + k0 + ksA, a_s[buf] + ldsoff0);
    gld_lds16(Bt + (size_t)(n0 + row0) * K + k0 + ks0, b_s[buf] + ldsoff0);
    gld_lds16(Bt + (size_t)(n0 + row1) * K + k0 + ks1, b_s[buf] + ldsoff1);
  };

  f32x4 acc[4][2] = {};

  stage(0, 0);
  asm volatile("s_waitcnt vmcnt(0)" ::: "memory");
  __syncthreads();

  for (int kt = 0; kt < nk; ++kt) {
    const int cur = kt & 1;
    const bool more = (kt + 1) < nk;
    if (more) stage(kt + 1, cur ^ 1);

    short8 af[4], bf[2];
#pragma unroll
    for (int mi = 0; mi < 4; ++mi) {
      int row = mi*16 + l16;
      int sw = quad ^ ((row >> 1) & 3);
      af[mi] = *(const short8*)(a_s[cur] + row * 32 + sw * 8);
    }
#pragma unroll
    for (int ni = 0; ni < 2; ++ni) {
      int row = wid*32 + ni*16 + l16;
      int sw = quad ^ ((row >> 1) & 3);
      bf[ni] = *(const short8*)(b_s[cur] + row * 32 + sw * 8);
    }
#pragma unroll
    for (int mi = 0; mi < 4; ++mi)
#pragma unroll
      for (int ni = 0; ni < 2; ++ni)
        acc[mi][ni] = __builtin_amdgcn_mfma_f32_16x16x32_bf16(af[mi], bf[ni], acc[mi][ni], 0, 0, 0);

    if (more) {
      asm volatile("s_waitcnt vmcnt(0)" ::: "memory");
      __syncthreads();
    }
  }

#pragma unroll
  for (int mi = 0; mi < 4; ++mi) {
#pragma unroll
    for (int ni = 0; ni < 2; ++ni) {
      int nn = n0 + wid*32 + ni * 16 + l16;
#pragma unroll
      for (int r = 0; r < 4; ++r) {
        int mm = m0 + mi * 16 + quad * 4 + r;
        float add = acc[mi][ni][r] + (bias ? bias[nn] : 0.f);
        Cr[(size_t)mm * N + nn] += add;         // single writer
      }
    }
  }
}

// ------------------------------- attention ----------------------------------
// block = (qt 64-row tile, head, batch); 4 waves, wave = 16 q-rows, k-tile 64.
// Computes S^T = mfma(A=K, B=Q): lane's 4 regs = 4 consecutive keys of one
// q-row -> P written as 4 x ds_write_b64 per kt; rowsum is lane-local scalar.
__global__ __launch_bounds__(256, 4)
void attn_kernel(const short* __restrict__ qkv, const short* __restrict__ vt,
                 short* __restrict__ att, const int* __restrict__ n_events) {
  __shared__ short q_s[64 * 64];     // [qrow][d], chunk-swizzled, wave-private bands
  __shared__ short k_s[64 * 64];     // [krow][d], chunk-swizzled
  __shared__ short vt_s[64 * 64];    // [d][key],  chunk-swizzled
  __shared__ short p_s[64 * 68];     // [qrow][key], pad +4, wave-private bands
  const int tid = threadIdx.x, wid = tid >> 6, lane = tid & 63;
  const int quad = lane >> 4, l16 = lane & 15;
  const int qt = blockIdx.x, h = blockIdx.y, b = blockIdx.z;
  const int ne = n_events[b];
  const int qbase = b * E + qt * 64;

  // stage this wave's own 16 Q rows (wave-private -> no barrier needed)
#pragma unroll
  for (int r = 0; r < 2; ++r) {
    int row = wid * 16 + r * 8 + (lane >> 3);
    int sz = lane & 7, dc = sz ^ (row & 7);
    gld_lds16(qkv + (size_t)(qbase + row) * 1536 + h * 64 + dc * 8,
              q_s + (wid * 16 + r * 8) * 64);
  }
  asm volatile("s_waitcnt vmcnt(0)" ::: "memory");

  short8 qf[2];                      // Q fragment (B-operand): loop-invariant
#pragma unroll
  for (int ks = 0; ks < 2; ++ks) {
    int row = wid * 16 + l16;
    int dc = (ks * 4 + quad) ^ (row & 7);
    qf[ks] = *(const short8*)(q_s + row * 64 + dc * 8);
  }

  f32x4 accO[4] = {};
  float rs = 0.f;                    // lane-local: sum over this lane's keys

  for (int kt = 0; kt < 16; ++kt) {
    __syncthreads();                         // prev iter done with k_s/vt_s
#pragma unroll
    for (int r = 0; r < 2; ++r) {
      int i = (r*4 + wid) * 64 + lane;
      int row = i >> 3, sz = i & 7, dc = sz ^ (row & 7);
      gld_lds16(qkv + (size_t)(b * E + kt * 64 + row) * 1536 + 512 + h * 64 + dc * 8,
                k_s + (r*4 + wid) * 512);
      gld_lds16(vt + (size_t)((b * 8 + h) * 64 + row) * 1024 + kt * 64 + dc * 8,
                vt_s + (r*4 + wid) * 512);
    }
    asm volatile("s_waitcnt vmcnt(0)" ::: "memory");
    __syncthreads();

    // ---- S^T = K Q^T: D[m=key][n=q], base-2 logits ----
    f32x4 accS[4] = {};
#pragma unroll
    for (int ni = 0; ni < 4; ++ni) {
#pragma unroll
      for (int ks = 0; ks < 2; ++ks) {
        int row = ni * 16 + l16;
        int dc = (ks * 4 + quad) ^ (row & 7);
        short8 kf = *(const short8*)(k_s + row * 64 + dc * 8);
        accS[ni] = __builtin_amdgcn_mfma_f32_16x16x32_bf16(kf, qf[ks], accS[ni], 0, 0, 0);
      }
    }

    // ---- softmax numerator (no max subtraction; logits O(1)) ----
    bool full = (kt * 64 + 64) <= ne;        // block-uniform branch
#pragma unroll
    for (int ni = 0; ni < 4; ++ni) {
      float p[4];
#pragma unroll
      for (int r = 0; r < 4; ++r) {
        bool masked = !full && (kt * 64 + ni * 16 + quad * 4 + r) >= ne;
        p[r] = masked ? 0.f : __builtin_amdgcn_exp2f(accS[ni][r]);
        rs += p[r];
      }
      unsigned w0 = bfpack(p[0], p[1]), w1 = bfpack(p[2], p[3]);
      int2 pk; pk.x = (int)w0; pk.y = (int)w1;
      *(int2*)(p_s + (wid * 16 + l16) * 68 + ni * 16 + quad * 4) = pk;
    }
    // p_s is wave-private: DS ops in-order within a wave -> no barrier.

    // ---- O += P V ----
    short8 ap[2];
#pragma unroll
    for (int ks = 0; ks < 2; ++ks)
      ap[ks] = *(const short8*)(p_s + (wid * 16 + l16) * 68 + ks * 32 + quad * 8);
#pragma unroll
    for (int di = 0; di < 4; ++di) {
#pragma unroll
      for (int ks = 0; ks < 2; ++ks) {
        int dd = di * 16 + l16;
        int dc = (ks * 4 + quad) ^ (dd & 7);
        short8 bv = *(const short8*)(vt_s + dd * 64 + dc * 8);
        accO[di] = __builtin_amdgcn_mfma_f32_16x16x32_bf16(ap[ks], bv, accO[di], 0, 0, 0);
      }
    }
  }

  // denom: reduce across the 4 quads (lanes sharing q = l16), then distribute
  rs += __shfl_xor(rs, 16);
  rs += __shfl_xor(rs, 32);
#pragma unroll
  for (int r = 0; r < 4; ++r) {
    float dv = __shfl(rs, quad * 4 + r);     // denom of q-row quad*4+r
    float linv = 1.f / (dv > 0.f ? dv : 1.f);
    int mm = qbase + wid * 16 + quad * 4 + r;
#pragma unroll
    for (int di = 0; di < 4; ++di)
      att[(size_t)mm * D + h * 64 + di * 16 + l16] = f2bf(accO[di][r] * linv);
  }
}

// ------------------------------ masked pool ---------------------------------
__global__ void pool_kernel(const float* __restrict__ tmp, const int* __restrict__ nev,
                            float* __restrict__ out) {
  __shared__ float red[512];
  int b = blockIdx.x >> 6, ch = blockIdx.x & 63;
  int n = nev[b];
  float inv = 1.f / (float)(n > 0 ? n : 1);
  int tid = threadIdx.x;
  int col = (tid & 127) * 4;
  int r0 = ch * 16 + (tid >> 7);
  f32x4 s = {0.f, 0.f, 0.f, 0.f};
#pragma unroll
  for (int i = 0; i < 8; ++i) {
    int e = r0 + i * 2;
    if (e < n) s += *(const f32x4*)(tmp + ((size_t)(b * E + e)) * D + col);
  }
  if (tid >= 128) *(f32x4*)(red + (tid - 128) * 4) = s;
  __syncthreads();
  if (tid < 128) {
    s += *(const f32x4*)(red + tid * 4);
#pragma unroll
    for (int j = 0; j < 4; ++j) atomicAdd(&out[b * D + col + j], s[j] * inv);
  }
}

// ------------------------------- launcher -----------------------------------
extern "C" void kernel_launch(void* const* d_in, const int* in_sizes, int n_in,
                              void* d_out, int out_size, void* d_ws, size_t ws_size,
                              hipStream_t stream) {
  (void)in_sizes; (void)n_in; (void)ws_size;
  const float* x      = (const float*)d_in[0];
  const float* proj_w = (const float*)d_in[1];
  const float* proj_b = (const float*)d_in[2];
  const float* wq     = (const float*)d_in[3];
  const float* wk     = (const float*)d_in[4];
  const float* wv     = (const float*)d_in[5];
  const float* wo     = (const float*)d_in[6];
  const float* ln1_g  = (const float*)d_in[7];
  const float* ln1_b  = (const float*)d_in[8];
  const float* w1     = (const float*)d_in[9];
  const float* b1     = (const float*)d_in[10];
  const float* w2     = (const float*)d_in[11];
  const float* b2     = (const float*)d_in[12];
  const float* ln2_g  = (const float*)d_in[13];
  const float* ln2_b  = (const float*)d_in[14];
  const float* lnf_g  = (const float*)d_in[15];
  const float* lnf_b  = (const float*)d_in[16];

  char* ws = (char*)d_ws;
  float* h      = (float*)(ws + OFF_H);
  short* z      = (short*)(ws + OFF_Z);
  short* qkv    = (short*)(ws + OFF_QKV);
  short* att    = (short*)(ws + OFF_ATT);
  short* u      = (short*)(ws + OFF_U);
  short* vt     = (short*)(ws + OFF_U);      // alias: live only QKV->attn
  float* tmp    = (float*)(ws + OFF_U);      // alias: live only after last FFN
  short* wqkv_t = (short*)(ws + OFF_WQKV);
  short* wo_t   = (short*)(ws + OFF_WO);
  short* w1_t   = (short*)(ws + OFF_W1);
  short* w2_t   = (short*)(ws + OFF_W2);
  int4*  ev4    = (int4*)(ws + OFF_EV);
  int*   n_ev   = (int*)(ws + OFF_NEV);
  unsigned* xw  = (unsigned*)(ws + OFF_XW);

  tconv_all_kernel<<<12288, dim3(32,8), 0, stream>>>(wq, wk, wv, wo, w1, w2,
                                                     wqkv_t, wo_t, w1_t, w2_t);
  xpack_kernel<<<128, 256, 0, stream>>>(x, xw);
  events_kernel<<<8, 1024, 0, stream>>>(xw, ev4, n_ev);
  embed_kernel<<<M, 128, 0, stream>>>(ev4, n_ev, proj_w, proj_b, h);

  for (int l = 0; l < NL; ++l) {
    ln_kernel<0><<<2048, 256, 0, stream>>>(h, ln1_g + l*D, ln1_b + l*D, z);
    gemm_kernel<0><<<dim3(12,64), 256, 0, stream>>>(z, wqkv_t + (size_t)l*786432, nullptr, qkv, 1536, 512);
    vtrans_kernel<<<dim3(16,8,8), 256, 0, stream>>>(qkv, vt);
    attn_kernel<<<dim3(16,8,8), 256, 0, stream>>>(qkv, vt, att, n_ev);
    gemm64_kernel<<<dim3(4,128), 256, 0, stream>>>(att, wo_t + (size_t)l*262144, nullptr, h, 512, 512);
    ln_kernel<0><<<2048, 256, 0, stream>>>(h, ln2_g + l*D, ln2_b + l*D, z);
    gemm_kernel<1><<<dim3(16,64), 256, 0, stream>>>(z, w1_t + (size_t)l*1048576, b1 + l*F, u, 2048, 512);
    gemm64_kernel<<<dim3(4,128), 256, 0, stream>>>(u, w2_t + (size_t)l*1048576, b2 + l*D, h, 512, 2048);
  }

  ln_kernel<1><<<2048, 256, 0, stream>>>(h, lnf_g, lnf_b, tmp);
  hipMemsetAsync(d_out, 0, (size_t)out_size * sizeof(float), stream);
  pool_kernel<<<512, 256, 0, stream>>>(tmp, n_ev, (float*)d_out);
}

// Round 8
// 734.162 us; speedup vs baseline: 1.2935x; 1.0864x over previous
//
#include <hip/hip_runtime.h>
#include <cstdint>
#include <cstddef>

// ---------------------------------------------------------------------------
// RunLengthEventTransformerEmbedding  (B=8,T=4096,C=8,E=1024,D=512,F=2048,L=4)
// R8: XCD-grouped block mapping (n-tiles sharing an A m-slice -> same XCD L2)
//     for all GEMMs + attn; gemm64 BK=64 (half the barriers, 2x MFMA/sync).
// ---------------------------------------------------------------------------

typedef __attribute__((ext_vector_type(8))) short short8;   // 8 x bf16 (4 VGPR)
typedef __attribute__((ext_vector_type(4))) float f32x4;

#define DEVINL __device__ __forceinline__

DEVINL short f2bf(float f) {               // fp32 -> bf16 RNE (finite inputs)
  union { float f; unsigned u; } v; v.f = f;
  unsigned u = v.u + 0x7fffu + ((v.u >> 16) & 1u);
  return (short)(u >> 16);
}

DEVINL unsigned bfpack(float lo, float hi) {  // two fp32 -> packed bf16x2 (trunc)
  union { float f; unsigned u; } a, b; a.f = lo; b.f = hi;
  return (a.u >> 16) | (b.u & 0xFFFF0000u);
}

DEVINL void gld_lds16(const void* g, void* l) {
  // async global->LDS, 16B/lane; LDS dest is wave-uniform base + lane*16
  __builtin_amdgcn_global_load_lds(
      (const __attribute__((address_space(1))) void*)g,
      (__attribute__((address_space(3))) void*)l, 16, 0, 0);
}

// ----------------------------- constants -----------------------------------
static constexpr int Bq = 8, T = 4096, C = 8, E = 1024, D = 512, F = 2048;
static constexpr int NL = 4, NH = 8, DH = 64, M = Bq * E;   // 8192 tokens
static constexpr float QSCALE = 0.18033688011112042f;       // 0.125 * log2(e)

// workspace offsets (bytes)
static constexpr size_t OFF_H    = 0;                        // f32 [8192,512]  16MB
static constexpr size_t OFF_Z    = OFF_H    + (size_t)16*1024*1024;  // bf16 [8192,512]   8MB
static constexpr size_t OFF_QKV  = OFF_Z    + (size_t)8*1024*1024;   // bf16 [8192,1536] 24MB
static constexpr size_t OFF_ATT  = OFF_QKV  + (size_t)24*1024*1024;  // bf16 [8192,512]   8MB
static constexpr size_t OFF_U    = OFF_ATT  + (size_t)8*1024*1024;   // bf16 [8192,2048] 32MB
                                   // OFF_U doubles as: vt bf16 [8,8,64,1024] (8MB, during attn)
                                   // and f32 tmp [8192,512] (16MB, after last FFN)
static constexpr size_t OFF_WQKV = OFF_U    + (size_t)32*1024*1024;  // bf16 [4][1536,512] 6MB
static constexpr size_t OFF_WO   = OFF_WQKV + (size_t)6*1024*1024;   // bf16 [4][512,512]  2MB
static constexpr size_t OFF_W1   = OFF_WO   + (size_t)2*1024*1024;   // bf16 [4][2048,512] 8MB
static constexpr size_t OFF_W2   = OFF_W1   + (size_t)8*1024*1024;   // bf16 [4][512,2048] 8MB
static constexpr size_t OFF_EV   = OFF_W2   + (size_t)8*1024*1024;   // int4 events [8192] 128KB
static constexpr size_t OFF_NEV  = OFF_EV   + (size_t)131072;        // int [8]
static constexpr size_t OFF_XW   = OFF_NEV  + (size_t)256;           // u32 [8,1024] 32KB

// ------------------ fused weight transpose + bf16 convert -------------------
__global__ void tconv_all_kernel(const float* __restrict__ wq, const float* __restrict__ wk,
                                 const float* __restrict__ wv, const float* __restrict__ wo,
                                 const float* __restrict__ w1, const float* __restrict__ w2,
                                 short* __restrict__ wqkv_t, short* __restrict__ wo_t,
                                 short* __restrict__ w1_t, short* __restrict__ w2_t) {
  int bid = blockIdx.x;
  const float* src; short* dst; int N, K, tile;
  if (bid < 4096) {
    int which = bid >> 10, r = bid & 1023, l = r >> 8;
    tile = r & 255; N = 512; K = 512;
    switch (which) {
      case 0:  src = wq + (size_t)l*262144; dst = wqkv_t + (size_t)l*786432;          break;
      case 1:  src = wk + (size_t)l*262144; dst = wqkv_t + (size_t)l*786432 + 262144; break;
      case 2:  src = wv + (size_t)l*262144; dst = wqkv_t + (size_t)l*786432 + 524288; break;
      default: src = wo + (size_t)l*262144; dst = wo_t   + (size_t)l*262144;          break;
    }
  } else if (bid < 8192) {
    int r = bid - 4096, l = r >> 10; tile = r & 1023;
    N = 2048; K = 512;
    src = w1 + (size_t)l*1048576; dst = w1_t + (size_t)l*1048576;
  } else {
    int r = bid - 8192, l = r >> 10; tile = r & 1023;
    N = 512; K = 2048;
    src = w2 + (size_t)l*1048576; dst = w2_t + (size_t)l*1048576;
  }
  int tiles_n = N >> 5;
  int n0 = (tile % tiles_n) * 32, k0 = (tile / tiles_n) * 32;
  __shared__ float tile_s[32][33];
  int tx = threadIdx.x, ty = threadIdx.y;
#pragma unroll
  for (int s = 0; s < 4; ++s)
    tile_s[ty + 8*s][tx] = src[(size_t)(k0 + ty + 8*s) * N + n0 + tx];
  __syncthreads();
#pragma unroll
  for (int s = 0; s < 4; ++s)
    dst[(size_t)(n0 + ty + 8*s) * K + k0 + tx] = f2bf(tile_s[tx][ty + 8*s]);
}

// ------------------------------ bit packing ---------------------------------
__global__ void xpack_kernel(const float* __restrict__ x, unsigned* __restrict__ xw) {
  __shared__ unsigned char sb[256];
  int idx = blockIdx.x * 256 + threadIdx.x;    // byte index = b*4096 + t
  const float* p = x + (size_t)idx * 8;
  f32x4 a = *(const f32x4*)p, b = *(const f32x4*)(p + 4);
  unsigned byte = 0;
#pragma unroll
  for (int j = 0; j < 4; ++j) {
    byte |= (a[j] > 0.5f ? 1u : 0u) << j;
    byte |= (b[j] > 0.5f ? 1u : 0u) << (j + 4);
  }
  sb[threadIdx.x] = (unsigned char)byte;
  __syncthreads();
  if (threadIdx.x < 64)
    xw[blockIdx.x * 64 + threadIdx.x] = *(const unsigned*)(sb + threadIdx.x * 4);
}

// ------------------------------ event scan ----------------------------------
__global__ void events_kernel(const unsigned* __restrict__ xw,
                              int4* __restrict__ ev4, int* __restrict__ n_events) {
  int b = blockIdx.x, tid = threadIdx.x;
  int lane = tid & 63, wid = tid >> 6;
  __shared__ int wsum[16];
  const unsigned* xb = xw + b * 1024;
  unsigned word = xb[tid];
  unsigned prevtop = (tid > 0) ? (xb[tid - 1] >> 24) : 0u;
  unsigned flags = word ^ ((word << 8) | prevtop);
  if (tid == 0) flags |= 0xFFu;                 // t=0: every component starts
  int cnt = __builtin_popcount(flags);

  int v = cnt;                                  // wave inclusive scan
#pragma unroll
  for (int off = 1; off < 64; off <<= 1) {
    int u = __shfl_up(v, off);
    if (lane >= off) v += u;
  }
  if (lane == 63) wsum[wid] = v;
  __syncthreads();
  int base = 0;
  for (int w = 0; w < wid; ++w) base += wsum[w];
  if (tid == 1023) {
    int tot = base + v;
    n_events[b] = tot < E ? tot : E;
  }
  int rank = base + v - cnt;

  unsigned f = flags;
  while (f && rank < E) {
    int bit = __builtin_ctz(f); f &= f - 1;
    int tl = bit >> 3, c = bit & 7;
    int t = tid * 4 + tl;
    int st = (word >> bit) & 1;
    unsigned colm = 0x01010101u << c;
    unsigned above = (bit < 31) ? (flags & colm & (0xFFFFFFFFu << (bit + 1))) : 0u;
    int t2;
    if (above) {
      int nb = __builtin_ctz(above);
      t2 = tid * 4 + ((nb - c) >> 3);
    } else {
      t2 = T;
      for (int w2 = tid + 1; w2 < 1024; ++w2) {
        unsigned nw = xb[w2];
        unsigned fl2 = nw ^ ((nw << 8) | (xb[w2 - 1] >> 24));
        unsigned m2 = fl2 & colm;
        if (m2) { t2 = w2 * 4 + ((__builtin_ctz(m2) - c) >> 3); break; }
      }
    }
    ev4[(b << 10) + rank] = make_int4(c, st, t, t2 - t);
    ++rank;
  }
}

// ------------------------------- embedding ----------------------------------
__global__ void embed_kernel(const int4* __restrict__ ev4, const int* __restrict__ nev,
                             const float* __restrict__ pw, const float* __restrict__ pb,
                             float* __restrict__ h) {
  int row = blockIdx.x;
  int b = row >> 10, e = row & 1023;
  int d = threadIdx.x * 4;
  f32x4 acc = *(const f32x4*)(pb + d);
  if (e < nev[b]) {
    int4 e4 = ev4[row];
    float st = (float)e4.y;
    float sn = (float)e4.z * (1.f / 4095.f);
    float dn = (float)e4.w * (1.f / 4096.f);
    acc += *(const f32x4*)(pw + e4.x * D + d);
    acc += st * *(const f32x4*)(pw + 8*D + d);
    acc += sn * *(const f32x4*)(pw + 9*D + d);
    acc += dn * *(const f32x4*)(pw + 10*D + d);
  }
  *(f32x4*)(h + (size_t)row * D + d) = acc;
}

// ------------------------------- layernorm ----------------------------------
template<int OUTF>
__global__ void ln_kernel(const float* __restrict__ hp, const float* __restrict__ g,
                          const float* __restrict__ bb, void* __restrict__ out) {
  int row = blockIdx.x * 4 + (threadIdx.x >> 6);
  int lane = threadIdx.x & 63;
  int c0 = lane * 8;
  const float* hr = hp + (size_t)row * D;
  f32x4 a = *(const f32x4*)(hr + c0);
  f32x4 c = *(const f32x4*)(hr + c0 + 4);
  float s1 = a[0]+a[1]+a[2]+a[3] + c[0]+c[1]+c[2]+c[3];
  float s2 = a[0]*a[0]+a[1]*a[1]+a[2]*a[2]+a[3]*a[3]
           + c[0]*c[0]+c[1]*c[1]+c[2]*c[2]+c[3]*c[3];
#pragma unroll
  for (int off = 1; off < 64; off <<= 1) {
    s1 += __shfl_xor(s1, off);
    s2 += __shfl_xor(s2, off);
  }
  float mean = s1 * (1.f / 512.f);
  float var  = s2 * (1.f / 512.f) - mean * mean;
  float rstd = rsqrtf(var + 1e-5f);
  f32x4 g0 = *(const f32x4*)(g + c0),  g1 = *(const f32x4*)(g + c0 + 4);
  f32x4 b0 = *(const f32x4*)(bb + c0), b1 = *(const f32x4*)(bb + c0 + 4);
  f32x4 o0 = (a - mean) * rstd * g0 + b0;
  f32x4 o1 = (c - mean) * rstd * g1 + b1;
  if constexpr (OUTF == 0) {
    short8 o;
#pragma unroll
    for (int j = 0; j < 4; ++j) { o[j] = f2bf(o0[j]); o[4 + j] = f2bf(o1[j]); }
    *(short8*)((short*)out + (size_t)row * D + c0) = o;
  } else {
    float* op = (float*)out + (size_t)row * D + c0;
    *(f32x4*)op = o0;
    *(f32x4*)(op + 4) = o1;
  }
}

// ------------------------- V transpose (bf16) --------------------------------
__global__ void vtrans_kernel(const short* __restrict__ qkv, short* __restrict__ vt) {
  __shared__ short st[64 * 72];
  int et = blockIdx.x, h = blockIdx.y, b = blockIdx.z;
  int tid = threadIdx.x;
  int r8 = tid >> 3, c8 = (tid & 7) * 8;
#pragma unroll
  for (int p = 0; p < 2; ++p) {
    int e = r8 + p * 32;
    short8 v = *(const short8*)(qkv + (size_t)(b*1024 + et*64 + e) * 1536 + 1024 + h*64 + c8);
#pragma unroll
    for (int j = 0; j < 8; ++j) st[(c8 + j) * 72 + e] = v[j];
  }
  __syncthreads();
#pragma unroll
  for (int p = 0; p < 2; ++p) {
    int dd = r8 + p * 32;
    short8 o = *(const short8*)(st + dd * 72 + c8);
    *(short8*)(vt + ((size_t)((b*8 + h) * 64 + dd)) * 1024 + et * 64 + c8) = o;
  }
}

// ----------------------------- GEMM (128x128) --------------------------------
// C[M,N] = A[M,K] @ Bt[N,K]^T, bf16 in, fp32 acc. 4 waves x 64x64, pipelined
// dbuf (1 barrier/iter), XOR bank swizzle. 1D grid, XCD-grouped mapping:
// the NX n-tiles sharing an m-slice have bids == same (mod 8) -> same XCD L2.
// MODE 0: bf16 store (cols<512 scaled by QSCALE). MODE 1: bias + fast GELU.
template<int MODE, int NX>
__global__ __launch_bounds__(256, 4)
void gemm_kernel(const short* __restrict__ A, const short* __restrict__ Bt,
                 const float* __restrict__ bias, short* __restrict__ O1,
                 int N, int K) {
  __shared__ short a_s[2][128 * 32];
  __shared__ short b_s[2][128 * 32];
  const int tid = threadIdx.x;
  const int wid = tid >> 6, lane = tid & 63;
  const int quad = lane >> 4, l16 = lane & 15;
  const int bid = blockIdx.x;
  const int xcd = bid & 7, q = bid >> 3;
  const int m0 = ((q / NX) * 8 + xcd) * 128, n0 = (q % NX) * 128;
  const int wrow = wid >> 1, wcol = wid & 1;
  const int nk = K >> 5;

  const int row0 = tid >> 2, kc0 = tid & 3;          // chunk i = tid
  const int row1 = (tid + 256) >> 2;                 // chunk i = tid + 256
  const int ks0 = (kc0 ^ ((row0 >> 1) & 3)) * 8;     // swizzled k-offset (shorts)
  const int ks1 = (kc0 ^ ((row1 >> 1) & 3)) * 8;
  const int ldsoff0 = tid * 8 - lane * 8;            // wave-uniform base
  const int ldsoff1 = (tid + 256) * 8 - lane * 8;

  auto stage = [&](int kt, int buf) {
    int k0 = kt * 32;
    gld_lds16(A  + (size_t)(m0 + row0) * K + k0 + ks0, a_s[buf] + ldsoff0);
    gld_lds16(A  + (size_t)(m0 + row1) * K + k0 + ks1, a_s[buf] + ldsoff1);
    gld_lds16(Bt + (size_t)(n0 + row0) * K + k0 + ks0, b_s[buf] + ldsoff0);
    gld_lds16(Bt + (size_t)(n0 + row1) * K + k0 + ks1, b_s[buf] + ldsoff1);
  };

  f32x4 acc[4][4] = {};

  stage(0, 0);
  asm volatile("s_waitcnt vmcnt(0)" ::: "memory");
  __syncthreads();

  for (int kt = 0; kt < nk; ++kt) {
    const int cur = kt & 1;
    const bool more = (kt + 1) < nk;
    if (more) stage(kt + 1, cur ^ 1);

    short8 af[4], bf[4];
#pragma unroll
    for (int mi = 0; mi < 4; ++mi) {
      int row = wrow*64 + mi*16 + l16;
      int sw = quad ^ ((row >> 1) & 3);
      af[mi] = *(const short8*)(a_s[cur] + row * 32 + sw * 8);
    }
#pragma unroll
    for (int ni = 0; ni < 4; ++ni) {
      int row = wcol*64 + ni*16 + l16;
      int sw = quad ^ ((row >> 1) & 3);
      bf[ni] = *(const short8*)(b_s[cur] + row * 32 + sw * 8);
    }
#pragma unroll
    for (int mi = 0; mi < 4; ++mi)
#pragma unroll
      for (int ni = 0; ni < 4; ++ni)
        acc[mi][ni] = __builtin_amdgcn_mfma_f32_16x16x32_bf16(af[mi], bf[ni], acc[mi][ni], 0, 0, 0);

    if (more) {
      asm volatile("s_waitcnt vmcnt(0)" ::: "memory");
      __syncthreads();
    }
  }

  const int mb = m0 + wrow * 64, nb = n0 + wcol * 64;
#pragma unroll
  for (int mi = 0; mi < 4; ++mi) {
#pragma unroll
    for (int ni = 0; ni < 4; ++ni) {
      int nn = nb + ni * 16 + l16;
#pragma unroll
      for (int r = 0; r < 4; ++r) {
        int mm = mb + mi * 16 + quad * 4 + r;   // C/D: col=lane&15, row=quad*4+reg
        float cv = acc[mi][ni][r];
        if constexpr (MODE == 0) {
          float ov = (nn < 512) ? cv * QSCALE : cv;  // fold softmax scale*log2e into Q
          union { float f; unsigned u; } vv; vv.f = ov;
          O1[(size_t)mm * N + nn] = (short)(vv.u >> 16);
        } else {
          float xv = cv + bias[nn];
          float x3 = xv * (1.f + 0.044715f * xv * xv);
          float ez = __builtin_amdgcn_exp2f(-2.3022082299f * x3);
          float gv = xv * __builtin_amdgcn_rcpf(1.f + ez);
          union { float f; unsigned u; } vv; vv.f = gv;
          O1[(size_t)mm * N + nn] = (short)(vv.u >> 16);
        }
      }
    }
  }
}

// ------------------------- GEMM 64x128 (residual) ----------------------------
// N=512 outputs: tile 64m x 128n, BK=64 (16 MFMA per sync), dbuf, 512 blocks.
// XCD-grouped: the 4 n-tiles of an m-slice land on one XCD. fp32 single-writer
// residual += (+bias). Swizzle: k-chunk slot = kc ^ (row & 7) (2-way = free).
__global__ __launch_bounds__(256, 3)
void gemm64_kernel(const short* __restrict__ A, const short* __restrict__ Bt,
                   const float* __restrict__ bias, float* __restrict__ Cr,
                   int N, int K) {
  __shared__ short a_s[2][64 * 64];
  __shared__ short b_s[2][128 * 64];
  const int tid = threadIdx.x;
  const int wid = tid >> 6, lane = tid & 63;
  const int quad = lane >> 4, l16 = lane & 15;
  const int bid = blockIdx.x;
  const int xcd = bid & 7, q = bid >> 3;
  const int m0 = ((q >> 2) * 8 + xcd) * 64, n0 = (q & 3) * 128;
  const int nk = K >> 6;

  auto stage = [&](int kt, int buf) {
    int k0 = kt * 64;
#pragma unroll
    for (int j = 0; j < 2; ++j) {
      int i = tid + j * 256;
      int row = i >> 3, kc = i & 7;
      int ks = (kc ^ (row & 7)) * 8;
      gld_lds16(A + (size_t)(m0 + row) * K + k0 + ks, a_s[buf] + i * 8 - lane * 8);
    }
#pragma unroll
    for (int j = 0; j < 4; ++j) {
      int i = tid + j * 256;
      int row = i >> 3, kc = i & 7;
      int ks = (kc ^ (row & 7)) * 8;
      gld_lds16(Bt + (size_t)(n0 + row) * K + k0 + ks, b_s[buf] + i * 8 - lane * 8);
    }
  };

  f32x4 acc[4][2] = {};

  stage(0, 0);
  asm volatile("s_waitcnt vmcnt(0)" ::: "memory");
  __syncthreads();

  for (int kt = 0; kt < nk; ++kt) {
    const int cur = kt & 1;
    const bool more = (kt + 1) < nk;
    if (more) stage(kt + 1, cur ^ 1);

    short8 af[4][2], bf[2][2];
#pragma unroll
    for (int mi = 0; mi < 4; ++mi) {
      int row = mi*16 + l16;
#pragma unroll
      for (int ks = 0; ks < 2; ++ks) {
        int sw = (ks * 4 + quad) ^ (row & 7);
        af[mi][ks] = *(const short8*)(a_s[cur] + row * 64 + sw * 8);
      }
    }
#pragma unroll
    for (int ni = 0; ni < 2; ++ni) {
      int row = wid*32 + ni*16 + l16;
#pragma unroll
      for (int ks = 0; ks < 2; ++ks) {
        int sw = (ks * 4 + quad) ^ (row & 7);
        bf[ni][ks] = *(const short8*)(b_s[cur] + row * 64 + sw * 8);
      }
    }
#pragma unroll
    for (int mi = 0; mi < 4; ++mi)
#pragma unroll
      for (int ni = 0; ni < 2; ++ni)
#pragma unroll
        for (int ks = 0; ks < 2; ++ks)
          acc[mi][ni] = __builtin_amdgcn_mfma_f32_16x16x32_bf16(af[mi][ks], bf[ni][ks], acc[mi][ni], 0, 0, 0);

    if (more) {
      asm volatile("s_waitcnt vmcnt(0)" ::: "memory");
      __syncthreads();
    }
  }

#pragma unroll
  for (int mi = 0; mi < 4; ++mi) {
#pragma unroll
    for (int ni = 0; ni < 2; ++ni) {
      int nn = n0 + wid*32 + ni * 16 + l16;
#pragma unroll
      for (int r = 0; r < 4; ++r) {
        int mm = m0 + mi * 16 + quad * 4 + r;
        float add = acc[mi][ni][r] + (bias ? bias[nn] : 0.f);
        Cr[(size_t)mm * N + nn] += add;         // single writer
      }
    }
  }
}

// ------------------------------- attention ----------------------------------
// 1D grid 1024, XCD-grouped: 16 qt-tiles sharing a (b,h) KV slice -> same XCD.
// 4 waves, wave = 16 q-rows, k-tile 64. S^T = mfma(A=K, B=Q); P via b64 LDS
// writes; lane-local rowsum; base-2 logits (Q pre-scaled); no max tracking.
__global__ __launch_bounds__(256, 4)
void attn_kernel(const short* __restrict__ qkv, const short* __restrict__ vt,
                 short* __restrict__ att, const int* __restrict__ n_events) {
  __shared__ short q_s[64 * 64];     // [qrow][d], chunk-swizzled, wave-private bands
  __shared__ short k_s[64 * 64];     // [krow][d], chunk-swizzled
  __shared__ short vt_s[64 * 64];    // [d][key],  chunk-swizzled
  __shared__ short p_s[64 * 68];     // [qrow][key], pad +4, wave-private bands
  const int tid = threadIdx.x, wid = tid >> 6, lane = tid & 63;
  const int quad = lane >> 4, l16 = lane & 15;
  const int bid = blockIdx.x;
  const int xcd = bid & 7, qq = bid >> 3;      // qq in [0,128)
  const int qt = qq & 15;
  const int bh = (qq >> 4) * 8 + xcd;          // [0,64): b*8+h
  const int b = bh >> 3, h = bh & 7;
  const int ne = n_events[b];
  const int qbase = b * E + qt * 64;

  // stage this wave's own 16 Q rows (wave-private -> no barrier needed)
#pragma unroll
  for (int r = 0; r < 2; ++r) {
    int row = wid * 16 + r * 8 + (lane >> 3);
    int sz = lane & 7, dc = sz ^ (row & 7);
    gld_lds16(qkv + (size_t)(qbase + row) * 1536 + h * 64 + dc * 8,
              q_s + (wid * 16 + r * 8) * 64);
  }
  asm volatile("s_waitcnt vmcnt(0)" ::: "memory");

  short8 qf[2];                      // Q fragment (B-operand): loop-invariant
#pragma unroll
  for (int ks = 0; ks < 2; ++ks) {
    int row = wid * 16 + l16;
    int dc = (ks * 4 + quad) ^ (row & 7);
    qf[ks] = *(const short8*)(q_s + row * 64 + dc * 8);
  }

  f32x4 accO[4] = {};
  float rs = 0.f;                    // lane-local: sum over this lane's keys

  for (int kt = 0; kt < 16; ++kt) {
    __syncthreads();                         // prev iter done with k_s/vt_s
#pragma unroll
    for (int r = 0; r < 2; ++r) {
      int i = (r*4 + wid) * 64 + lane;
      int row = i >> 3, sz = i & 7, dc = sz ^ (row & 7);
      gld_lds16(qkv + (size_t)(b * E + kt * 64 + row) * 1536 + 512 + h * 64 + dc * 8,
                k_s + (r*4 + wid) * 512);
      gld_lds16(vt + (size_t)((b * 8 + h) * 64 + row) * 1024 + kt * 64 + dc * 8,
                vt_s + (r*4 + wid) * 512);
    }
    asm volatile("s_waitcnt vmcnt(0)" ::: "memory");
    __syncthreads();

    // ---- S^T = K Q^T: D[m=key][n=q], base-2 logits ----
    f32x4 accS[4] = {};
#pragma unroll
    for (int ni = 0; ni < 4; ++ni) {
#pragma unroll
      for (int ks = 0; ks < 2; ++ks) {
        int row = ni * 16 + l16;
        int dc = (ks * 4 + quad) ^ (row & 7);
        short8 kf = *(const short8*)(k_s + row * 64 + dc * 8);
        accS[ni] = __builtin_amdgcn_mfma_f32_16x16x32_bf16(kf, qf[ks], accS[ni], 0, 0, 0);
      }
    }

    // ---- softmax numerator (no max subtraction; logits O(1)) ----
    bool full = (kt * 64 + 64) <= ne;        // block-uniform branch
#pragma unroll
    for (int ni = 0; ni < 4; ++ni) {
      float p[4];
#pragma unroll
      for (int r = 0; r < 4; ++r) {
        bool masked = !full && (kt * 64 + ni * 16 + quad * 4 + r) >= ne;
        p[r] = masked ? 0.f : __builtin_amdgcn_exp2f(accS[ni][r]);
        rs += p[r];
      }
      unsigned w0 = bfpack(p[0], p[1]), w1 = bfpack(p[2], p[3]);
      int2 pk; pk.x = (int)w0; pk.y = (int)w1;
      *(int2*)(p_s + (wid * 16 + l16) * 68 + ni * 16 + quad * 4) = pk;
    }
    // p_s is wave-private: DS ops in-order within a wave -> no barrier.

    // ---- O += P V ----
    short8 ap[2];
#pragma unroll
    for (int ks = 0; ks < 2; ++ks)
      ap[ks] = *(const short8*)(p_s + (wid * 16 + l16) * 68 + ks * 32 + quad * 8);
#pragma unroll
    for (int di = 0; di < 4; ++di) {
#pragma unroll
      for (int ks = 0; ks < 2; ++ks) {
        int dd = di * 16 + l16;
        int dc = (ks * 4 + quad) ^ (dd & 7);
        short8 bv = *(const short8*)(vt_s + dd * 64 + dc * 8);
        accO[di] = __builtin_amdgcn_mfma_f32_16x16x32_bf16(ap[ks], bv, accO[di], 0, 0, 0);
      }
    }
  }

  // denom: reduce across the 4 quads (lanes sharing q = l16), then distribute
  rs += __shfl_xor(rs, 16);
  rs += __shfl_xor(rs, 32);
#pragma unroll
  for (int r = 0; r < 4; ++r) {
    float dv = __shfl(rs, quad * 4 + r);     // denom of q-row quad*4+r
    float linv = 1.f / (dv > 0.f ? dv : 1.f);
    int mm = qbase + wid * 16 + quad * 4 + r;
#pragma unroll
    for (int di = 0; di < 4; ++di)
      att[(size_t)mm * D + h * 64 + di * 16 + l16] = f2bf(accO[di][r] * linv);
  }
}

// ------------------------------ masked pool ---------------------------------
__global__ void pool_kernel(const float* __restrict__ tmp, const int* __restrict__ nev,
                            float* __restrict__ out) {
  __shared__ float red[512];
  int b = blockIdx.x >> 6, ch = blockIdx.x & 63;
  int n = nev[b];
  float inv = 1.f / (float)(n > 0 ? n : 1);
  int tid = threadIdx.x;
  int col = (tid & 127) * 4;
  int r0 = ch * 16 + (tid >> 7);
  f32x4 s = {0.f, 0.f, 0.f, 0.f};
#pragma unroll
  for (int i = 0; i < 8; ++i) {
    int e = r0 + i * 2;
    if (e < n) s += *(const f32x4*)(tmp + ((size_t)(b * E + e)) * D + col);
  }
  if (tid >= 128) *(f32x4*)(red + (tid - 128) * 4) = s;
  __syncthreads();
  if (tid < 128) {
    s += *(const f32x4*)(red + tid * 4);
#pragma unroll
    for (int j = 0; j < 4; ++j) atomicAdd(&out[b * D + col + j], s[j] * inv);
  }
}

// ------------------------------- launcher -----------------------------------
extern "C" void kernel_launch(void* const* d_in, const int* in_sizes, int n_in,
                              void* d_out, int out_size, void* d_ws, size_t ws_size,
                              hipStream_t stream) {
  (void)in_sizes; (void)n_in; (void)ws_size;
  const float* x      = (const float*)d_in[0];
  const float* proj_w = (const float*)d_in[1];
  const float* proj_b = (const float*)d_in[2];
  const float* wq     = (const float*)d_in[3];
  const float* wk     = (const float*)d_in[4];
  const float* wv     = (const float*)d_in[5];
  const float* wo     = (const float*)d_in[6];
  const float* ln1_g  = (const float*)d_in[7];
  const float* ln1_b  = (const float*)d_in[8];
  const float* w1     = (const float*)d_in[9];
  const float* b1     = (const float*)d_in[10];
  const float* w2     = (const float*)d_in[11];
  const float* b2     = (const float*)d_in[12];
  const float* ln2_g  = (const float*)d_in[13];
  const float* ln2_b  = (const float*)d_in[14];
  const float* lnf_g  = (const float*)d_in[15];
  const float* lnf_b  = (const float*)d_in[16];

  char* ws = (char*)d_ws;
  float* h      = (float*)(ws + OFF_H);
  short* z      = (short*)(ws + OFF_Z);
  short* qkv    = (short*)(ws + OFF_QKV);
  short* att    = (short*)(ws + OFF_ATT);
  short* u      = (short*)(ws + OFF_U);
  short* vt     = (short*)(ws + OFF_U);      // alias: live only QKV->attn
  float* tmp    = (float*)(ws + OFF_U);      // alias: live only after last FFN
  short* wqkv_t = (short*)(ws + OFF_WQKV);
  short* wo_t   = (short*)(ws + OFF_WO);
  short* w1_t   = (short*)(ws + OFF_W1);
  short* w2_t   = (short*)(ws + OFF_W2);
  int4*  ev4    = (int4*)(ws + OFF_EV);
  int*   n_ev   = (int*)(ws + OFF_NEV);
  unsigned* xw  = (unsigned*)(ws + OFF_XW);

  tconv_all_kernel<<<12288, dim3(32,8), 0, stream>>>(wq, wk, wv, wo, w1, w2,
                                                     wqkv_t, wo_t, w1_t, w2_t);
  xpack_kernel<<<128, 256, 0, stream>>>(x, xw);
  events_kernel<<<8, 1024, 0, stream>>>(xw, ev4, n_ev);
  embed_kernel<<<M, 128, 0, stream>>>(ev4, n_ev, proj_w, proj_b, h);

  for (int l = 0; l < NL; ++l) {
    ln_kernel<0><<<2048, 256, 0, stream>>>(h, ln1_g + l*D, ln1_b + l*D, z);
    gemm_kernel<0,12><<<768, 256, 0, stream>>>(z, wqkv_t + (size_t)l*786432, nullptr, qkv, 1536, 512);
    vtrans_kernel<<<dim3(16,8,8), 256, 0, stream>>>(qkv, vt);
    attn_kernel<<<1024, 256, 0, stream>>>(qkv, vt, att, n_ev);
    gemm64_kernel<<<512, 256, 0, stream>>>(att, wo_t + (size_t)l*262144, nullptr, h, 512, 512);
    ln_kernel<0><<<2048, 256, 0, stream>>>(h, ln2_g + l*D, ln2_b + l*D, z);
    gemm_kernel<1,16><<<1024, 256, 0, stream>>>(z, w1_t + (size_t)l*1048576, b1 + l*F, u, 2048, 512);
    gemm64_kernel<<<512, 256, 0, stream>>>(u, w2_t + (size_t)l*1048576, b2 + l*D, h, 512, 2048);
  }

  ln_kernel<1><<<2048, 256, 0, stream>>>(h, lnf_g, lnf_b, tmp);
  hipMemsetAsync(d_out, 0, (size_t)out_size * sizeof(float), stream);
  pool_kernel<<<512, 256, 0, stream>>>(tmp, n_ev, (float*)d_out);
}

// Round 9
// 692.509 us; speedup vs baseline: 1.3713x; 1.0601x over previous
//
#include <hip/hip_runtime.h>
#include <cstdint>
#include <cstddef>

// ---------------------------------------------------------------------------
// RunLengthEventTransformerEmbedding  (B=8,T=4096,C=8,E=1024,D=512,F=2048,L=4)
// R9: gemm64 -> 64x64 tiles, 1024 blocks = 4/CU (grid was the occupancy cap
//     at 512), BK=64 dbuf 32KB LDS, 2x2 wave quadrants. XCD grouping kept.
// ---------------------------------------------------------------------------

typedef __attribute__((ext_vector_type(8))) short short8;   // 8 x bf16 (4 VGPR)
typedef __attribute__((ext_vector_type(4))) float f32x4;

#define DEVINL __device__ __forceinline__

DEVINL short f2bf(float f) {               // fp32 -> bf16 RNE (finite inputs)
  union { float f; unsigned u; } v; v.f = f;
  unsigned u = v.u + 0x7fffu + ((v.u >> 16) & 1u);
  return (short)(u >> 16);
}

DEVINL unsigned bfpack(float lo, float hi) {  // two fp32 -> packed bf16x2 (trunc)
  union { float f; unsigned u; } a, b; a.f = lo; b.f = hi;
  return (a.u >> 16) | (b.u & 0xFFFF0000u);
}

DEVINL void gld_lds16(const void* g, void* l) {
  // async global->LDS, 16B/lane; LDS dest is wave-uniform base + lane*16
  __builtin_amdgcn_global_load_lds(
      (const __attribute__((address_space(1))) void*)g,
      (__attribute__((address_space(3))) void*)l, 16, 0, 0);
}

// ----------------------------- constants -----------------------------------
static constexpr int Bq = 8, T = 4096, C = 8, E = 1024, D = 512, F = 2048;
static constexpr int NL = 4, NH = 8, DH = 64, M = Bq * E;   // 8192 tokens
static constexpr float QSCALE = 0.18033688011112042f;       // 0.125 * log2(e)

// workspace offsets (bytes)
static constexpr size_t OFF_H    = 0;                        // f32 [8192,512]  16MB
static constexpr size_t OFF_Z    = OFF_H    + (size_t)16*1024*1024;  // bf16 [8192,512]   8MB
static constexpr size_t OFF_QKV  = OFF_Z    + (size_t)8*1024*1024;   // bf16 [8192,1536] 24MB
static constexpr size_t OFF_ATT  = OFF_QKV  + (size_t)24*1024*1024;  // bf16 [8192,512]   8MB
static constexpr size_t OFF_U    = OFF_ATT  + (size_t)8*1024*1024;   // bf16 [8192,2048] 32MB
                                   // OFF_U doubles as: vt bf16 [8,8,64,1024] (8MB, during attn)
                                   // and f32 tmp [8192,512] (16MB, after last FFN)
static constexpr size_t OFF_WQKV = OFF_U    + (size_t)32*1024*1024;  // bf16 [4][1536,512] 6MB
static constexpr size_t OFF_WO   = OFF_WQKV + (size_t)6*1024*1024;   // bf16 [4][512,512]  2MB
static constexpr size_t OFF_W1   = OFF_WO   + (size_t)2*1024*1024;   // bf16 [4][2048,512] 8MB
static constexpr size_t OFF_W2   = OFF_W1   + (size_t)8*1024*1024;   // bf16 [4][512,2048] 8MB
static constexpr size_t OFF_EV   = OFF_W2   + (size_t)8*1024*1024;   // int4 events [8192] 128KB
static constexpr size_t OFF_NEV  = OFF_EV   + (size_t)131072;        // int [8]
static constexpr size_t OFF_XW   = OFF_NEV  + (size_t)256;           // u32 [8,1024] 32KB

// ------------------ fused weight transpose + bf16 convert -------------------
__global__ void tconv_all_kernel(const float* __restrict__ wq, const float* __restrict__ wk,
                                 const float* __restrict__ wv, const float* __restrict__ wo,
                                 const float* __restrict__ w1, const float* __restrict__ w2,
                                 short* __restrict__ wqkv_t, short* __restrict__ wo_t,
                                 short* __restrict__ w1_t, short* __restrict__ w2_t) {
  int bid = blockIdx.x;
  const float* src; short* dst; int N, K, tile;
  if (bid < 4096) {
    int which = bid >> 10, r = bid & 1023, l = r >> 8;
    tile = r & 255; N = 512; K = 512;
    switch (which) {
      case 0:  src = wq + (size_t)l*262144; dst = wqkv_t + (size_t)l*786432;          break;
      case 1:  src = wk + (size_t)l*262144; dst = wqkv_t + (size_t)l*786432 + 262144; break;
      case 2:  src = wv + (size_t)l*262144; dst = wqkv_t + (size_t)l*786432 + 524288; break;
      default: src = wo + (size_t)l*262144; dst = wo_t   + (size_t)l*262144;          break;
    }
  } else if (bid < 8192) {
    int r = bid - 4096, l = r >> 10; tile = r & 1023;
    N = 2048; K = 512;
    src = w1 + (size_t)l*1048576; dst = w1_t + (size_t)l*1048576;
  } else {
    int r = bid - 8192, l = r >> 10; tile = r & 1023;
    N = 512; K = 2048;
    src = w2 + (size_t)l*1048576; dst = w2_t + (size_t)l*1048576;
  }
  int tiles_n = N >> 5;
  int n0 = (tile % tiles_n) * 32, k0 = (tile / tiles_n) * 32;
  __shared__ float tile_s[32][33];
  int tx = threadIdx.x, ty = threadIdx.y;
#pragma unroll
  for (int s = 0; s < 4; ++s)
    tile_s[ty + 8*s][tx] = src[(size_t)(k0 + ty + 8*s) * N + n0 + tx];
  __syncthreads();
#pragma unroll
  for (int s = 0; s < 4; ++s)
    dst[(size_t)(n0 + ty + 8*s) * K + k0 + tx] = f2bf(tile_s[tx][ty + 8*s]);
}

// ------------------------------ bit packing ---------------------------------
__global__ void xpack_kernel(const float* __restrict__ x, unsigned* __restrict__ xw) {
  __shared__ unsigned char sb[256];
  int idx = blockIdx.x * 256 + threadIdx.x;    // byte index = b*4096 + t
  const float* p = x + (size_t)idx * 8;
  f32x4 a = *(const f32x4*)p, b = *(const f32x4*)(p + 4);
  unsigned byte = 0;
#pragma unroll
  for (int j = 0; j < 4; ++j) {
    byte |= (a[j] > 0.5f ? 1u : 0u) << j;
    byte |= (b[j] > 0.5f ? 1u : 0u) << (j + 4);
  }
  sb[threadIdx.x] = (unsigned char)byte;
  __syncthreads();
  if (threadIdx.x < 64)
    xw[blockIdx.x * 64 + threadIdx.x] = *(const unsigned*)(sb + threadIdx.x * 4);
}

// ------------------------------ event scan ----------------------------------
__global__ void events_kernel(const unsigned* __restrict__ xw,
                              int4* __restrict__ ev4, int* __restrict__ n_events) {
  int b = blockIdx.x, tid = threadIdx.x;
  int lane = tid & 63, wid = tid >> 6;
  __shared__ int wsum[16];
  const unsigned* xb = xw + b * 1024;
  unsigned word = xb[tid];
  unsigned prevtop = (tid > 0) ? (xb[tid - 1] >> 24) : 0u;
  unsigned flags = word ^ ((word << 8) | prevtop);
  if (tid == 0) flags |= 0xFFu;                 // t=0: every component starts
  int cnt = __builtin_popcount(flags);

  int v = cnt;                                  // wave inclusive scan
#pragma unroll
  for (int off = 1; off < 64; off <<= 1) {
    int u = __shfl_up(v, off);
    if (lane >= off) v += u;
  }
  if (lane == 63) wsum[wid] = v;
  __syncthreads();
  int base = 0;
  for (int w = 0; w < wid; ++w) base += wsum[w];
  if (tid == 1023) {
    int tot = base + v;
    n_events[b] = tot < E ? tot : E;
  }
  int rank = base + v - cnt;

  unsigned f = flags;
  while (f && rank < E) {
    int bit = __builtin_ctz(f); f &= f - 1;
    int tl = bit >> 3, c = bit & 7;
    int t = tid * 4 + tl;
    int st = (word >> bit) & 1;
    unsigned colm = 0x01010101u << c;
    unsigned above = (bit < 31) ? (flags & colm & (0xFFFFFFFFu << (bit + 1))) : 0u;
    int t2;
    if (above) {
      int nb = __builtin_ctz(above);
      t2 = tid * 4 + ((nb - c) >> 3);
    } else {
      t2 = T;
      for (int w2 = tid + 1; w2 < 1024; ++w2) {
        unsigned nw = xb[w2];
        unsigned fl2 = nw ^ ((nw << 8) | (xb[w2 - 1] >> 24));
        unsigned m2 = fl2 & colm;
        if (m2) { t2 = w2 * 4 + ((__builtin_ctz(m2) - c) >> 3); break; }
      }
    }
    ev4[(b << 10) + rank] = make_int4(c, st, t, t2 - t);
    ++rank;
  }
}

// ------------------------------- embedding ----------------------------------
__global__ void embed_kernel(const int4* __restrict__ ev4, const int* __restrict__ nev,
                             const float* __restrict__ pw, const float* __restrict__ pb,
                             float* __restrict__ h) {
  int row = blockIdx.x;
  int b = row >> 10, e = row & 1023;
  int d = threadIdx.x * 4;
  f32x4 acc = *(const f32x4*)(pb + d);
  if (e < nev[b]) {
    int4 e4 = ev4[row];
    float st = (float)e4.y;
    float sn = (float)e4.z * (1.f / 4095.f);
    float dn = (float)e4.w * (1.f / 4096.f);
    acc += *(const f32x4*)(pw + e4.x * D + d);
    acc += st * *(const f32x4*)(pw + 8*D + d);
    acc += sn * *(const f32x4*)(pw + 9*D + d);
    acc += dn * *(const f32x4*)(pw + 10*D + d);
  }
  *(f32x4*)(h + (size_t)row * D + d) = acc;
}

// ------------------------------- layernorm ----------------------------------
template<int OUTF>
__global__ void ln_kernel(const float* __restrict__ hp, const float* __restrict__ g,
                          const float* __restrict__ bb, void* __restrict__ out) {
  int row = blockIdx.x * 4 + (threadIdx.x >> 6);
  int lane = threadIdx.x & 63;
  int c0 = lane * 8;
  const float* hr = hp + (size_t)row * D;
  f32x4 a = *(const f32x4*)(hr + c0);
  f32x4 c = *(const f32x4*)(hr + c0 + 4);
  float s1 = a[0]+a[1]+a[2]+a[3] + c[0]+c[1]+c[2]+c[3];
  float s2 = a[0]*a[0]+a[1]*a[1]+a[2]*a[2]+a[3]*a[3]
           + c[0]*c[0]+c[1]*c[1]+c[2]*c[2]+c[3]*c[3];
#pragma unroll
  for (int off = 1; off < 64; off <<= 1) {
    s1 += __shfl_xor(s1, off);
    s2 += __shfl_xor(s2, off);
  }
  float mean = s1 * (1.f / 512.f);
  float var  = s2 * (1.f / 512.f) - mean * mean;
  float rstd = rsqrtf(var + 1e-5f);
  f32x4 g0 = *(const f32x4*)(g + c0),  g1 = *(const f32x4*)(g + c0 + 4);
  f32x4 b0 = *(const f32x4*)(bb + c0), b1 = *(const f32x4*)(bb + c0 + 4);
  f32x4 o0 = (a - mean) * rstd * g0 + b0;
  f32x4 o1 = (c - mean) * rstd * g1 + b1;
  if constexpr (OUTF == 0) {
    short8 o;
#pragma unroll
    for (int j = 0; j < 4; ++j) { o[j] = f2bf(o0[j]); o[4 + j] = f2bf(o1[j]); }
    *(short8*)((short*)out + (size_t)row * D + c0) = o;
  } else {
    float* op = (float*)out + (size_t)row * D + c0;
    *(f32x4*)op = o0;
    *(f32x4*)(op + 4) = o1;
  }
}

// ------------------------- V transpose (bf16) --------------------------------
__global__ void vtrans_kernel(const short* __restrict__ qkv, short* __restrict__ vt) {
  __shared__ short st[64 * 72];
  int et = blockIdx.x, h = blockIdx.y, b = blockIdx.z;
  int tid = threadIdx.x;
  int r8 = tid >> 3, c8 = (tid & 7) * 8;
#pragma unroll
  for (int p = 0; p < 2; ++p) {
    int e = r8 + p * 32;
    short8 v = *(const short8*)(qkv + (size_t)(b*1024 + et*64 + e) * 1536 + 1024 + h*64 + c8);
#pragma unroll
    for (int j = 0; j < 8; ++j) st[(c8 + j) * 72 + e] = v[j];
  }
  __syncthreads();
#pragma unroll
  for (int p = 0; p < 2; ++p) {
    int dd = r8 + p * 32;
    short8 o = *(const short8*)(st + dd * 72 + c8);
    *(short8*)(vt + ((size_t)((b*8 + h) * 64 + dd)) * 1024 + et * 64 + c8) = o;
  }
}

// ----------------------------- GEMM (128x128) --------------------------------
// C[M,N] = A[M,K] @ Bt[N,K]^T, bf16 in, fp32 acc. 4 waves x 64x64, pipelined
// dbuf (1 barrier/iter), XOR bank swizzle. 1D grid, XCD-grouped mapping.
// MODE 0: bf16 store (cols<512 scaled by QSCALE). MODE 1: bias + fast GELU.
template<int MODE, int NX>
__global__ __launch_bounds__(256, 4)
void gemm_kernel(const short* __restrict__ A, const short* __restrict__ Bt,
                 const float* __restrict__ bias, short* __restrict__ O1,
                 int N, int K) {
  __shared__ short a_s[2][128 * 32];
  __shared__ short b_s[2][128 * 32];
  const int tid = threadIdx.x;
  const int wid = tid >> 6, lane = tid & 63;
  const int quad = lane >> 4, l16 = lane & 15;
  const int bid = blockIdx.x;
  const int xcd = bid & 7, q = bid >> 3;
  const int m0 = ((q / NX) * 8 + xcd) * 128, n0 = (q % NX) * 128;
  const int wrow = wid >> 1, wcol = wid & 1;
  const int nk = K >> 5;

  const int row0 = tid >> 2, kc0 = tid & 3;          // chunk i = tid
  const int row1 = (tid + 256) >> 2;                 // chunk i = tid + 256
  const int ks0 = (kc0 ^ ((row0 >> 1) & 3)) * 8;     // swizzled k-offset (shorts)
  const int ks1 = (kc0 ^ ((row1 >> 1) & 3)) * 8;
  const int ldsoff0 = tid * 8 - lane * 8;            // wave-uniform base
  const int ldsoff1 = (tid + 256) * 8 - lane * 8;

  auto stage = [&](int kt, int buf) {
    int k0 = kt * 32;
    gld_lds16(A  + (size_t)(m0 + row0) * K + k0 + ks0, a_s[buf] + ldsoff0);
    gld_lds16(A  + (size_t)(m0 + row1) * K + k0 + ks1, a_s[buf] + ldsoff1);
    gld_lds16(Bt + (size_t)(n0 + row0) * K + k0 + ks0, b_s[buf] + ldsoff0);
    gld_lds16(Bt + (size_t)(n0 + row1) * K + k0 + ks1, b_s[buf] + ldsoff1);
  };

  f32x4 acc[4][4] = {};

  stage(0, 0);
  asm volatile("s_waitcnt vmcnt(0)" ::: "memory");
  __syncthreads();

  for (int kt = 0; kt < nk; ++kt) {
    const int cur = kt & 1;
    const bool more = (kt + 1) < nk;
    if (more) stage(kt + 1, cur ^ 1);

    short8 af[4], bf[4];
#pragma unroll
    for (int mi = 0; mi < 4; ++mi) {
      int row = wrow*64 + mi*16 + l16;
      int sw = quad ^ ((row >> 1) & 3);
      af[mi] = *(const short8*)(a_s[cur] + row * 32 + sw * 8);
    }
#pragma unroll
    for (int ni = 0; ni < 4; ++ni) {
      int row = wcol*64 + ni*16 + l16;
      int sw = quad ^ ((row >> 1) & 3);
      bf[ni] = *(const short8*)(b_s[cur] + row * 32 + sw * 8);
    }
#pragma unroll
    for (int mi = 0; mi < 4; ++mi)
#pragma unroll
      for (int ni = 0; ni < 4; ++ni)
        acc[mi][ni] = __builtin_amdgcn_mfma_f32_16x16x32_bf16(af[mi], bf[ni], acc[mi][ni], 0, 0, 0);

    if (more) {
      asm volatile("s_waitcnt vmcnt(0)" ::: "memory");
      __syncthreads();
    }
  }

  const int mb = m0 + wrow * 64, nb = n0 + wcol * 64;
#pragma unroll
  for (int mi = 0; mi < 4; ++mi) {
#pragma unroll
    for (int ni = 0; ni < 4; ++ni) {
      int nn = nb + ni * 16 + l16;
#pragma unroll
      for (int r = 0; r < 4; ++r) {
        int mm = mb + mi * 16 + quad * 4 + r;   // C/D: col=lane&15, row=quad*4+reg
        float cv = acc[mi][ni][r];
        if constexpr (MODE == 0) {
          float ov = (nn < 512) ? cv * QSCALE : cv;  // fold softmax scale*log2e into Q
          union { float f; unsigned u; } vv; vv.f = ov;
          O1[(size_t)mm * N + nn] = (short)(vv.u >> 16);
        } else {
          float xv = cv + bias[nn];
          float x3 = xv * (1.f + 0.044715f * xv * xv);
          float ez = __builtin_amdgcn_exp2f(-2.3022082299f * x3);
          float gv = xv * __builtin_amdgcn_rcpf(1.f + ez);
          union { float f; unsigned u; } vv; vv.f = gv;
          O1[(size_t)mm * N + nn] = (short)(vv.u >> 16);
        }
      }
    }
  }
}

// ------------------------- GEMM 64x64 (residual) -----------------------------
// N=512 outputs: tile 64m x 64n, BK=64, dbuf 32KB LDS -> 1024 blocks = 4/CU.
// 4 waves in 2x2 quadrants (each 32m x 32n: 8 ds_read + 8 MFMA per iter).
// XCD-grouped: the 8 n-tiles of an m-slice -> same XCD L2. fp32 single-writer
// residual += (+bias). Swizzle: k-chunk slot = kc ^ (row & 7) (2-way = free).
__global__ __launch_bounds__(256, 4)
void gemm64_kernel(const short* __restrict__ A, const short* __restrict__ Bt,
                   const float* __restrict__ bias, float* __restrict__ Cr,
                   int N, int K) {
  __shared__ short a_s[2][64 * 64];
  __shared__ short b_s[2][64 * 64];
  const int tid = threadIdx.x;
  const int wid = tid >> 6, lane = tid & 63;
  const int quad = lane >> 4, l16 = lane & 15;
  const int bid = blockIdx.x;
  const int xcd = bid & 7, q = bid >> 3;
  const int ntiles = N >> 6;                   // 8
  const int m0 = ((q / ntiles) * 8 + xcd) * 64, n0 = (q % ntiles) * 64;
  const int mh = wid >> 1, nh = wid & 1;       // wave quadrant
  const int nk = K >> 6;

  auto stage = [&](int kt, int buf) {
    int k0 = kt * 64;
#pragma unroll
    for (int j = 0; j < 2; ++j) {
      int i = tid + j * 256;                   // chunk in [0,512)
      int row = i >> 3, kc = i & 7;
      int ks = (kc ^ (row & 7)) * 8;
      gld_lds16(A  + (size_t)(m0 + row) * K + k0 + ks, a_s[buf] + i * 8 - lane * 8);
      gld_lds16(Bt + (size_t)(n0 + row) * K + k0 + ks, b_s[buf] + i * 8 - lane * 8);
    }
  };

  f32x4 acc[2][2] = {};

  stage(0, 0);
  asm volatile("s_waitcnt vmcnt(0)" ::: "memory");
  __syncthreads();

  for (int kt = 0; kt < nk; ++kt) {
    const int cur = kt & 1;
    const bool more = (kt + 1) < nk;
    if (more) stage(kt + 1, cur ^ 1);

    short8 af[2][2], bf[2][2];
#pragma unroll
    for (int mi = 0; mi < 2; ++mi) {
      int row = mh*32 + mi*16 + l16;
#pragma unroll
      for (int ks = 0; ks < 2; ++ks) {
        int sw = (ks * 4 + quad) ^ (row & 7);
        af[mi][ks] = *(const short8*)(a_s[cur] + row * 64 + sw * 8);
      }
    }
#pragma unroll
    for (int ni = 0; ni < 2; ++ni) {
      int row = nh*32 + ni*16 + l16;
#pragma unroll
      for (int ks = 0; ks < 2; ++ks) {
        int sw = (ks * 4 + quad) ^ (row & 7);
        bf[ni][ks] = *(const short8*)(b_s[cur] + row * 64 + sw * 8);
      }
    }
#pragma unroll
    for (int mi = 0; mi < 2; ++mi)
#pragma unroll
      for (int ni = 0; ni < 2; ++ni)
#pragma unroll
        for (int ks = 0; ks < 2; ++ks)
          acc[mi][ni] = __builtin_amdgcn_mfma_f32_16x16x32_bf16(af[mi][ks], bf[ni][ks], acc[mi][ni], 0, 0, 0);

    if (more) {
      asm volatile("s_waitcnt vmcnt(0)" ::: "memory");
      __syncthreads();
    }
  }

#pragma unroll
  for (int mi = 0; mi < 2; ++mi) {
#pragma unroll
    for (int ni = 0; ni < 2; ++ni) {
      int nn = n0 + nh*32 + ni * 16 + l16;
#pragma unroll
      for (int r = 0; r < 4; ++r) {
        int mm = m0 + mh*32 + mi * 16 + quad * 4 + r;
        float add = acc[mi][ni][r] + (bias ? bias[nn] : 0.f);
        Cr[(size_t)mm * N + nn] += add;         // single writer
      }
    }
  }
}

// ------------------------------- attention ----------------------------------
// 1D grid 1024, XCD-grouped: 16 qt-tiles sharing a (b,h) KV slice -> same XCD.
// 4 waves, wave = 16 q-rows, k-tile 64. S^T = mfma(A=K, B=Q); P via b64 LDS
// writes; lane-local rowsum; base-2 logits (Q pre-scaled); no max tracking.
__global__ __launch_bounds__(256, 4)
void attn_kernel(const short* __restrict__ qkv, const short* __restrict__ vt,
                 short* __restrict__ att, const int* __restrict__ n_events) {
  __shared__ short q_s[64 * 64];     // [qrow][d], chunk-swizzled, wave-private bands
  __shared__ short k_s[64 * 64];     // [krow][d], chunk-swizzled
  __shared__ short vt_s[64 * 64];    // [d][key],  chunk-swizzled
  __shared__ short p_s[64 * 68];     // [qrow][key], pad +4, wave-private bands
  const int tid = threadIdx.x, wid = tid >> 6, lane = tid & 63;
  const int quad = lane >> 4, l16 = lane & 15;
  const int bid = blockIdx.x;
  const int xcd = bid & 7, qq = bid >> 3;      // qq in [0,128)
  const int qt = qq & 15;
  const int bh = (qq >> 4) * 8 + xcd;          // [0,64): b*8+h
  const int b = bh >> 3, h = bh & 7;
  const int ne = n_events[b];
  const int qbase = b * E + qt * 64;

  // stage this wave's own 16 Q rows (wave-private -> no barrier needed)
#pragma unroll
  for (int r = 0; r < 2; ++r) {
    int row = wid * 16 + r * 8 + (lane >> 3);
    int sz = lane & 7, dc = sz ^ (row & 7);
    gld_lds16(qkv + (size_t)(qbase + row) * 1536 + h * 64 + dc * 8,
              q_s + (wid * 16 + r * 8) * 64);
  }
  asm volatile("s_waitcnt vmcnt(0)" ::: "memory");

  short8 qf[2];                      // Q fragment (B-operand): loop-invariant
#pragma unroll
  for (int ks = 0; ks < 2; ++ks) {
    int row = wid * 16 + l16;
    int dc = (ks * 4 + quad) ^ (row & 7);
    qf[ks] = *(const short8*)(q_s + row * 64 + dc * 8);
  }

  f32x4 accO[4] = {};
  float rs = 0.f;                    // lane-local: sum over this lane's keys

  for (int kt = 0; kt < 16; ++kt) {
    __syncthreads();                         // prev iter done with k_s/vt_s
#pragma unroll
    for (int r = 0; r < 2; ++r) {
      int i = (r*4 + wid) * 64 + lane;
      int row = i >> 3, sz = i & 7, dc = sz ^ (row & 7);
      gld_lds16(qkv + (size_t)(b * E + kt * 64 + row) * 1536 + 512 + h * 64 + dc * 8,
                k_s + (r*4 + wid) * 512);
      gld_lds16(vt + (size_t)((b * 8 + h) * 64 + row) * 1024 + kt * 64 + dc * 8,
                vt_s + (r*4 + wid) * 512);
    }
    asm volatile("s_waitcnt vmcnt(0)" ::: "memory");
    __syncthreads();

    // ---- S^T = K Q^T: D[m=key][n=q], base-2 logits ----
    f32x4 accS[4] = {};
#pragma unroll
    for (int ni = 0; ni < 4; ++ni) {
#pragma unroll
      for (int ks = 0; ks < 2; ++ks) {
        int row = ni * 16 + l16;
        int dc = (ks * 4 + quad) ^ (row & 7);
        short8 kf = *(const short8*)(k_s + row * 64 + dc * 8);
        accS[ni] = __builtin_amdgcn_mfma_f32_16x16x32_bf16(kf, qf[ks], accS[ni], 0, 0, 0);
      }
    }

    // ---- softmax numerator (no max subtraction; logits O(1)) ----
    bool full = (kt * 64 + 64) <= ne;        // block-uniform branch
#pragma unroll
    for (int ni = 0; ni < 4; ++ni) {
      float p[4];
#pragma unroll
      for (int r = 0; r < 4; ++r) {
        bool masked = !full && (kt * 64 + ni * 16 + quad * 4 + r) >= ne;
        p[r] = masked ? 0.f : __builtin_amdgcn_exp2f(accS[ni][r]);
        rs += p[r];
      }
      unsigned w0 = bfpack(p[0], p[1]), w1 = bfpack(p[2], p[3]);
      int2 pk; pk.x = (int)w0; pk.y = (int)w1;
      *(int2*)(p_s + (wid * 16 + l16) * 68 + ni * 16 + quad * 4) = pk;
    }
    // p_s is wave-private: DS ops in-order within a wave -> no barrier.

    // ---- O += P V ----
    short8 ap[2];
#pragma unroll
    for (int ks = 0; ks < 2; ++ks)
      ap[ks] = *(const short8*)(p_s + (wid * 16 + l16) * 68 + ks * 32 + quad * 8);
#pragma unroll
    for (int di = 0; di < 4; ++di) {
#pragma unroll
      for (int ks = 0; ks < 2; ++ks) {
        int dd = di * 16 + l16;
        int dc = (ks * 4 + quad) ^ (dd & 7);
        short8 bv = *(const short8*)(vt_s + dd * 64 + dc * 8);
        accO[di] = __builtin_amdgcn_mfma_f32_16x16x32_bf16(ap[ks], bv, accO[di], 0, 0, 0);
      }
    }
  }

  // denom: reduce across the 4 quads (lanes sharing q = l16), then distribute
  rs += __shfl_xor(rs, 16);
  rs += __shfl_xor(rs, 32);
#pragma unroll
  for (int r = 0; r < 4; ++r) {
    float dv = __shfl(rs, quad * 4 + r);     // denom of q-row quad*4+r
    float linv = 1.f / (dv > 0.f ? dv : 1.f);
    int mm = qbase + wid * 16 + quad * 4 + r;
#pragma unroll
    for (int di = 0; di < 4; ++di)
      att[(size_t)mm * D + h * 64 + di * 16 + l16] = f2bf(accO[di][r] * linv);
  }
}

// ------------------------------ masked pool ---------------------------------
__global__ void pool_kernel(const float* __restrict__ tmp, const int* __restrict__ nev,
                            float* __restrict__ out) {
  __shared__ float red[512];
  int b = blockIdx.x >> 6, ch = blockIdx.x & 63;
  int n = nev[b];
  float inv = 1.f / (float)(n > 0 ? n : 1);
  int tid = threadIdx.x;
  int col = (tid & 127) * 4;
  int r0 = ch * 16 + (tid >> 7);
  f32x4 s = {0.f, 0.f, 0.f, 0.f};
#pragma unroll
  for (int i = 0; i < 8; ++i) {
    int e = r0 + i * 2;
    if (e < n) s += *(const f32x4*)(tmp + ((size_t)(b * E + e)) * D + col);
  }
  if (tid >= 128) *(f32x4*)(red + (tid - 128) * 4) = s;
  __syncthreads();
  if (tid < 128) {
    s += *(const f32x4*)(red + tid * 4);
#pragma unroll
    for (int j = 0; j < 4; ++j) atomicAdd(&out[b * D + col + j], s[j] * inv);
  }
}

// ------------------------------- launcher -----------------------------------
extern "C" void kernel_launch(void* const* d_in, const int* in_sizes, int n_in,
                              void* d_out, int out_size, void* d_ws, size_t ws_size,
                              hipStream_t stream) {
  (void)in_sizes; (void)n_in; (void)ws_size;
  const float* x      = (const float*)d_in[0];
  const float* proj_w = (const float*)d_in[1];
  const float* proj_b = (const float*)d_in[2];
  const float* wq     = (const float*)d_in[3];
  const float* wk     = (const float*)d_in[4];
  const float* wv     = (const float*)d_in[5];
  const float* wo     = (const float*)d_in[6];
  const float* ln1_g  = (const float*)d_in[7];
  const float* ln1_b  = (const float*)d_in[8];
  const float* w1     = (const float*)d_in[9];
  const float* b1     = (const float*)d_in[10];
  const float* w2     = (const float*)d_in[11];
  const float* b2     = (const float*)d_in[12];
  const float* ln2_g  = (const float*)d_in[13];
  const float* ln2_b  = (const float*)d_in[14];
  const float* lnf_g  = (const float*)d_in[15];
  const float* lnf_b  = (const float*)d_in[16];

  char* ws = (char*)d_ws;
  float* h      = (float*)(ws + OFF_H);
  short* z      = (short*)(ws + OFF_Z);
  short* qkv    = (short*)(ws + OFF_QKV);
  short* att    = (short*)(ws + OFF_ATT);
  short* u      = (short*)(ws + OFF_U);
  short* vt     = (short*)(ws + OFF_U);      // alias: live only QKV->attn
  float* tmp    = (float*)(ws + OFF_U);      // alias: live only after last FFN
  short* wqkv_t = (short*)(ws + OFF_WQKV);
  short* wo_t   = (short*)(ws + OFF_WO);
  short* w1_t   = (short*)(ws + OFF_W1);
  short* w2_t   = (short*)(ws + OFF_W2);
  int4*  ev4    = (int4*)(ws + OFF_EV);
  int*   n_ev   = (int*)(ws + OFF_NEV);
  unsigned* xw  = (unsigned*)(ws + OFF_XW);

  tconv_all_kernel<<<12288, dim3(32,8), 0, stream>>>(wq, wk, wv, wo, w1, w2,
                                                     wqkv_t, wo_t, w1_t, w2_t);
  xpack_kernel<<<128, 256, 0, stream>>>(x, xw);
  events_kernel<<<8, 1024, 0, stream>>>(xw, ev4, n_ev);
  embed_kernel<<<M, 128, 0, stream>>>(ev4, n_ev, proj_w, proj_b, h);

  for (int l = 0; l < NL; ++l) {
    ln_kernel<0><<<2048, 256, 0, stream>>>(h, ln1_g + l*D, ln1_b + l*D, z);
    gemm_kernel<0,12><<<768, 256, 0, stream>>>(z, wqkv_t + (size_t)l*786432, nullptr, qkv, 1536, 512);
    vtrans_kernel<<<dim3(16,8,8), 256, 0, stream>>>(qkv, vt);
    attn_kernel<<<1024, 256, 0, stream>>>(qkv, vt, att, n_ev);
    gemm64_kernel<<<1024, 256, 0, stream>>>(att, wo_t + (size_t)l*262144, nullptr, h, 512, 512);
    ln_kernel<0><<<2048, 256, 0, stream>>>(h, ln2_g + l*D, ln2_b + l*D, z);
    gemm_kernel<1,16><<<1024, 256, 0, stream>>>(z, w1_t + (size_t)l*1048576, b1 + l*F, u, 2048, 512);
    gemm64_kernel<<<1024, 256, 0, stream>>>(u, w2_t + (size_t)l*1048576, b2 + l*D, h, 512, 2048);
  }

  ln_kernel<1><<<2048, 256, 0, stream>>>(h, lnf_g, lnf_b, tmp);
  hipMemsetAsync(d_out, 0, (size_t)out_size * sizeof(float), stream);
  pool_kernel<<<512, 256, 0, stream>>>(tmp, n_ev, (float*)d_out);
}